// Round 6
// baseline (949.363 us; speedup 1.0000x reference)
//
#include <hip/hip_runtime.h>

#define NF 481
#define NT 500
#define CH 16
#define HID 32
#define NB 16
#define NSEQ (NB*NF)   // 7696

typedef __attribute__((ext_vector_type(8))) short short8;
typedef __attribute__((ext_vector_type(4))) float f32x4;

// fast sigmoid — v_rcp instead of correctly-rounded divide (R10 win)
__device__ __forceinline__ float sig_(float v) {
    return __builtin_amdgcn_rcpf(1.0f + __expf(-v));
}

__device__ __forceinline__ unsigned short f2bf(float f) {
    unsigned u = __float_as_uint(f);
    u = (u + 0x7fffu + ((u >> 16) & 1u)) >> 16;   // RNE
    return (unsigned short)u;
}
__device__ __forceinline__ unsigned int pk2(float a, float b) {
    return (unsigned int)f2bf(a) | ((unsigned int)f2bf(b) << 16);
}
__device__ __forceinline__ float bf2f(short s) {
    return __uint_as_float(((unsigned)(unsigned short)s) << 16);
}
__device__ __forceinline__ float4 prelu4(float4 v, float a) {
    v.x = (v.x >= 0.f) ? v.x : a*v.x;
    v.y = (v.y >= 0.f) ? v.y : a*v.y;
    v.z = (v.z >= 0.f) ? v.z : a*v.z;
    v.w = (v.w >= 0.f) ? v.w : a*v.w;
    return v;
}

#define FMA4(Q, W, V)                     \
    Q.x = fmaf((W), (V).x, Q.x);          \
    Q.y = fmaf((W), (V).y, Q.y);          \
    Q.z = fmaf((W), (V).z, Q.z);          \
    Q.w = fmaf((W), (V).w, Q.w)

// -------------------------------------------------------------------------
// Pass 1: conv1(4->16,k9,p4) + PReLU -> y1 (b,f,t,ch) bf16.  (unchanged R5)
// -------------------------------------------------------------------------
#define P1TAP(D, K1)                                                           \
    {                                                                          \
        const int gf = f + (K1) - 4;                                           \
        if (gf >= 0 && gf < NF) {                                              \
            const float4 v = *(const float4*)(feat +                           \
                ((size_t)(b*4 + (D))*NF + gf)*NT + tc0);                       \
            FMA4(q0,  w1[ 0*36 + (D)*9 + (K1)], v);                            \
            FMA4(q1,  w1[ 1*36 + (D)*9 + (K1)], v);                            \
            FMA4(q2,  w1[ 2*36 + (D)*9 + (K1)], v);                            \
            FMA4(q3,  w1[ 3*36 + (D)*9 + (K1)], v);                            \
            FMA4(q4,  w1[ 4*36 + (D)*9 + (K1)], v);                            \
            FMA4(q5,  w1[ 5*36 + (D)*9 + (K1)], v);                            \
            FMA4(q6,  w1[ 6*36 + (D)*9 + (K1)], v);                            \
            FMA4(q7,  w1[ 7*36 + (D)*9 + (K1)], v);                            \
            FMA4(q8,  w1[ 8*36 + (D)*9 + (K1)], v);                            \
            FMA4(q9,  w1[ 9*36 + (D)*9 + (K1)], v);                            \
            FMA4(q10, w1[10*36 + (D)*9 + (K1)], v);                            \
            FMA4(q11, w1[11*36 + (D)*9 + (K1)], v);                            \
            FMA4(q12, w1[12*36 + (D)*9 + (K1)], v);                            \
            FMA4(q13, w1[13*36 + (D)*9 + (K1)], v);                            \
            FMA4(q14, w1[14*36 + (D)*9 + (K1)], v);                            \
            FMA4(q15, w1[15*36 + (D)*9 + (K1)], v);                            \
        }                                                                      \
    }

#define STX(OP, E, COMP)                                                       \
    *(uint4*)((OP) + (E)*CH) = make_uint4(                                     \
        pk2(q0.COMP, q1.COMP),  pk2(q2.COMP, q3.COMP),                         \
        pk2(q4.COMP, q5.COMP),  pk2(q6.COMP, q7.COMP));                        \
    *(uint4*)((OP) + (E)*CH + 8) = make_uint4(                                 \
        pk2(q8.COMP, q9.COMP),  pk2(q10.COMP, q11.COMP),                       \
        pk2(q12.COMP, q13.COMP), pk2(q14.COMP, q15.COMP))

__global__ __launch_bounds__(256) void conv1_kernel(
    const float* __restrict__ feat,
    const float* __restrict__ w1, const float* __restrict__ b1, const float* __restrict__ a1p,
    unsigned short* __restrict__ y1)          // (b, f, t, ch) bf16
{
    const int b    = blockIdx.x;
    const int wv   = threadIdx.x >> 6;
    const int lane = threadIdx.x & 63;
    const int f    = blockIdx.y*4 + wv;
    if (f >= NF) return;
    const int gt0  = blockIdx.z*256 + lane*4;
    const int tc0  = (gt0 <= NT-4) ? gt0 : (NT-4);
    const float al1 = a1p[0];

    float4 q0  = make_float4(b1[0],b1[0],b1[0],b1[0]);
    float4 q1  = make_float4(b1[1],b1[1],b1[1],b1[1]);
    float4 q2  = make_float4(b1[2],b1[2],b1[2],b1[2]);
    float4 q3  = make_float4(b1[3],b1[3],b1[3],b1[3]);
    float4 q4  = make_float4(b1[4],b1[4],b1[4],b1[4]);
    float4 q5  = make_float4(b1[5],b1[5],b1[5],b1[5]);
    float4 q6  = make_float4(b1[6],b1[6],b1[6],b1[6]);
    float4 q7  = make_float4(b1[7],b1[7],b1[7],b1[7]);
    float4 q8  = make_float4(b1[8],b1[8],b1[8],b1[8]);
    float4 q9  = make_float4(b1[9],b1[9],b1[9],b1[9]);
    float4 q10 = make_float4(b1[10],b1[10],b1[10],b1[10]);
    float4 q11 = make_float4(b1[11],b1[11],b1[11],b1[11]);
    float4 q12 = make_float4(b1[12],b1[12],b1[12],b1[12]);
    float4 q13 = make_float4(b1[13],b1[13],b1[13],b1[13]);
    float4 q14 = make_float4(b1[14],b1[14],b1[14],b1[14]);
    float4 q15 = make_float4(b1[15],b1[15],b1[15],b1[15]);

    #pragma unroll
    for (int d = 0; d < 4; d++) {
        P1TAP(d, 0); P1TAP(d, 1); P1TAP(d, 2); P1TAP(d, 3); P1TAP(d, 4);
        P1TAP(d, 5); P1TAP(d, 6); P1TAP(d, 7); P1TAP(d, 8);
    }

    if (gt0 < NT) {
        q0  = prelu4(q0,  al1); q1  = prelu4(q1,  al1);
        q2  = prelu4(q2,  al1); q3  = prelu4(q3,  al1);
        q4  = prelu4(q4,  al1); q5  = prelu4(q5,  al1);
        q6  = prelu4(q6,  al1); q7  = prelu4(q7,  al1);
        q8  = prelu4(q8,  al1); q9  = prelu4(q9,  al1);
        q10 = prelu4(q10, al1); q11 = prelu4(q11, al1);
        q12 = prelu4(q12, al1); q13 = prelu4(q13, al1);
        q14 = prelu4(q14, al1); q15 = prelu4(q15, al1);
        unsigned short* op = y1 + ((size_t)(b*NF + f)*NT + gt0)*CH;
        STX(op, 0, x); STX(op, 1, y); STX(op, 2, z); STX(op, 3, w);
    }
}

// -------------------------------------------------------------------------
// Pass 2: conv2(16->16,k5,p2) via MFMA + PReLU -> x (n,t,16).  (unchanged R5)
// -------------------------------------------------------------------------
__global__ __launch_bounds__(256) void conv2_kernel(
    const unsigned short* __restrict__ y1,    // (b, f, t, ch) bf16
    const float* __restrict__ w2, const float* __restrict__ b2, const float* __restrict__ a2p,
    unsigned short* __restrict__ xout)
{
    __shared__ unsigned short ylds[8*128*24];    // 48 KB: [row8][t128][ch16+pad8]
    const int b    = blockIdx.x;
    const int f0   = blockIdx.y * 4;
    const int tg   = blockIdx.z * 128;
    const int tid  = threadIdx.x;
    const int wid  = tid >> 6;
    const int lane = tid & 63;

    #pragma unroll
    for (int i = 0; i < 8; i++) {
        const int idx  = tid + i*256;        // 0..2047
        const int row  = idx >> 8;           // 0..7
        const int tt   = (idx >> 1) & 127;
        const int half = idx & 1;
        const int fr   = f0 - 2 + row;
        const int gt   = tg + tt;
        uint4 v = make_uint4(0u, 0u, 0u, 0u);
        if (fr >= 0 && fr < NF && gt < NT)
            v = *(const uint4*)(y1 + ((size_t)(b*NF + fr)*NT + gt)*CH + half*8);
        *(uint4*)&ylds[(row*128 + tt)*24 + half*8] = v;
    }
    __syncthreads();

    const int c    = lane & 15;
    const int quad = lane >> 4;
    const int f    = f0 + wid;
    if (f < NF) {
        const float al2 = a2p[0];
        short8 Bh0, Bh1, Bh2, Bl0, Bl1, Bl2;
        #define MKB2(BH, BL, Q)                                                \
            { _Pragma("unroll") for (int j = 0; j < 8; j++) {                  \
                const int ci = (quad & 1)*8 + j;                               \
                const int kk = 2*(Q) + (quad >> 1);                            \
                float w = 0.f;                                                 \
                if (kk < 5) w = w2[c*80 + ci*5 + kk];                          \
                const unsigned short hb = f2bf(w);                             \
                const float hf = bf2f((short)hb);                              \
                BH[j] = (short)hb;                                             \
                BL[j] = (short)f2bf(w - hf); } }
        MKB2(Bh0, Bl0, 0); MKB2(Bh1, Bl1, 1); MKB2(Bh2, Bl2, 2);
        #undef MKB2

        const f32x4 cb = {b2[c], b2[c], b2[c], b2[c]};
        const int ci0 = (quad & 1)*8;
        const int r0  = wid + (quad >> 1);
        unsigned short* xo = xout + ((size_t)(b*NF + f)*NT)*CH + c;

        #pragma unroll
        for (int ti = 0; ti < 8; ti++) {
            const int t = ti*16 + c;
            const int rl2 = (r0 + 4 > 7) ? 7 : (r0 + 4);
            const short8 a0 = *(const short8*)&ylds[((r0    )*128 + t)*24 + ci0];
            const short8 a1 = *(const short8*)&ylds[((r0 + 2)*128 + t)*24 + ci0];
            const short8 a2 = *(const short8*)&ylds[((rl2   )*128 + t)*24 + ci0];
            f32x4 acc = cb;
            acc = __builtin_amdgcn_mfma_f32_16x16x32_bf16(a0, Bl0, acc, 0, 0, 0);
            acc = __builtin_amdgcn_mfma_f32_16x16x32_bf16(a1, Bl1, acc, 0, 0, 0);
            acc = __builtin_amdgcn_mfma_f32_16x16x32_bf16(a2, Bl2, acc, 0, 0, 0);
            acc = __builtin_amdgcn_mfma_f32_16x16x32_bf16(a0, Bh0, acc, 0, 0, 0);
            acc = __builtin_amdgcn_mfma_f32_16x16x32_bf16(a1, Bh1, acc, 0, 0, 0);
            acc = __builtin_amdgcn_mfma_f32_16x16x32_bf16(a2, Bh2, acc, 0, 0, 0);
            #pragma unroll
            for (int r = 0; r < 4; r++) {
                const int tt = tg + ti*16 + quad*4 + r;
                if (tt < NT) {
                    float v = acc[r];
                    v = (v >= 0.f) ? v : al2*v;
                    xo[(size_t)tt*CH] = f2bf(v);
                }
            }
        }
    }
}

// -------------------------------------------------------------------------
// GRU via MFMA — R6: software dual-pipeline.  One wave carries TWO
// independent 16-seq groups (A, B) through the recurrence in one
// instruction stream.  B's MFMAs/GSTEP issue while A's dependency chains
// (ds round-trip ~240cy, MFMA latency, exp->rcp chains) are cooking — the
// ~1000 stall cyc/step measured at 29% VALUBusy get filled without any new
// barriers (R11's failure mode).  Weight fragments shared between groups.
// -------------------------------------------------------------------------
__global__ __launch_bounds__(64) void gru_kernel(
    const unsigned short* __restrict__ xin,  // (NSEQ, NT, 16) bf16
    const float* __restrict__ h0,    // (NSEQ, 32)
    const float* __restrict__ w_ih,  // (96, 16)
    const float* __restrict__ w_hh,  // (96, 32)
    const float* __restrict__ b_ih, const float* __restrict__ b_hh,
    const float* __restrict__ fc_w, const float* __restrict__ fc_b,
    float* __restrict__ prob,        // (NSEQ, NT)
    float* __restrict__ hout)        // (NSEQ, 32)
{
    __shared__ unsigned short svA[16*72];    // [seq][x16|h32|pad16] bf16
    __shared__ unsigned short svB[16*72];
    const int lane = threadIdx.x & 63;
    const int c    = lane & 15;
    const int quad = lane >> 4;
    const int baseA = blockIdx.x * 32;       // 241 blocks x 32 seq
    const int baseB = (baseA + 16 <= NSEQ - 16) ? (baseA + 16) : (NSEQ - 16);

    #define MKB(DST, G, CK)                                                    \
        { _Pragma("unroll") for (int j = 0; j < 8; j++) {                      \
            const int k = (CK)*32 + quad*8 + j;                                \
            const int g = (G);                                                 \
            float wv_;                                                         \
            if (g < 64)      wv_ = (k < 16) ? w_ih[g*16 + k]                   \
                                  : (k < 48) ? w_hh[g*32 + k - 16] : 0.f;      \
            else if (g < 96) wv_ = (k < 16) ? w_ih[g*16 + k] : 0.f;            \
            else             wv_ = (k >= 16 && k < 48)                         \
                                  ? w_hh[(g-32)*32 + k - 16] : 0.f;            \
            DST[j] = (short)f2bf(wv_); } }

    short8 B0a, B0b, B1a, B1b, B2a, B2b, B3a, B3b, B4a, B5a, B6a, B6b, B7a, B7b;
    MKB(B0a,       c, 0); MKB(B0b,       c, 1);   // r  units 0..15
    MKB(B1a,  16 + c, 0); MKB(B1b,  16 + c, 1);   // r  units 16..31
    MKB(B2a,  32 + c, 0); MKB(B2b,  32 + c, 1);   // z
    MKB(B3a,  48 + c, 0); MKB(B3b,  48 + c, 1);
    MKB(B4a,  64 + c, 0);                          // xn (chunk1 all-zero)
    MKB(B5a,  80 + c, 0);
    MKB(B6a,  96 + c, 0); MKB(B6b,  96 + c, 1);   // hn
    MKB(B7a, 112 + c, 0); MKB(B7b, 112 + c, 1);

    // FC fragment: same value in every col; k=16..47 <-> h units 0..31
    short8 Bfa, Bfb;
    { _Pragma("unroll") for (int j = 0; j < 8; j++) {
        const int k0 = quad*8 + j;
        Bfa[j] = (short)((k0 >= 16) ? f2bf(fc_w[k0 - 16]) : 0);
        const int k1 = 32 + quad*8 + j;
        Bfb[j] = (short)((k1 < 48) ? f2bf(fc_w[k1 - 16]) : 0);
    } }

    const float bi0 = b_ih[c]      + b_hh[c];
    const float bi1 = b_ih[16 + c] + b_hh[16 + c];
    const float bi2 = b_ih[32 + c] + b_hh[32 + c];
    const float bi3 = b_ih[48 + c] + b_hh[48 + c];
    const float bi4 = b_ih[64 + c];
    const float bi5 = b_ih[80 + c];
    const float bi6 = b_hh[64 + c];
    const float bi7 = b_hh[80 + c];
    const float fb = fc_b[0];

    const f32x4 cb0 = {bi0, bi0, bi0, bi0};
    const f32x4 cb1 = {bi1, bi1, bi1, bi1};
    const f32x4 cb2 = {bi2, bi2, bi2, bi2};
    const f32x4 cb3 = {bi3, bi3, bi3, bi3};
    const f32x4 cb4 = {bi4, bi4, bi4, bi4};
    const f32x4 cb5 = {bi5, bi5, bi5, bi5};
    const f32x4 cb6 = {bi6, bi6, bi6, bi6};
    const f32x4 cb7 = {bi7, bi7, bi7, bi7};
    const f32x4 cb8 = {fb, fb, fb, fb};

    // ---- per-group state (explicit names; no runtime-indexed arrays) ----
    float hA00 = h0[(size_t)(baseA + quad*4 + 0)*HID + c];
    float hA01 = h0[(size_t)(baseA + quad*4 + 0)*HID + 16 + c];
    float hA10 = h0[(size_t)(baseA + quad*4 + 1)*HID + c];
    float hA11 = h0[(size_t)(baseA + quad*4 + 1)*HID + 16 + c];
    float hA20 = h0[(size_t)(baseA + quad*4 + 2)*HID + c];
    float hA21 = h0[(size_t)(baseA + quad*4 + 2)*HID + 16 + c];
    float hA30 = h0[(size_t)(baseA + quad*4 + 3)*HID + c];
    float hA31 = h0[(size_t)(baseA + quad*4 + 3)*HID + 16 + c];
    float hB00 = h0[(size_t)(baseB + quad*4 + 0)*HID + c];
    float hB01 = h0[(size_t)(baseB + quad*4 + 0)*HID + 16 + c];
    float hB10 = h0[(size_t)(baseB + quad*4 + 1)*HID + c];
    float hB11 = h0[(size_t)(baseB + quad*4 + 1)*HID + 16 + c];
    float hB20 = h0[(size_t)(baseB + quad*4 + 2)*HID + c];
    float hB21 = h0[(size_t)(baseB + quad*4 + 2)*HID + 16 + c];
    float hB30 = h0[(size_t)(baseB + quad*4 + 3)*HID + c];
    float hB31 = h0[(size_t)(baseB + quad*4 + 3)*HID + 16 + c];

    // ---- init LDS buffers ----
    *(uint2*)&svA[(lane >> 2)*72 + 48 + (lane & 3)*4] = make_uint2(0u, 0u);
    *(uint2*)&svB[(lane >> 2)*72 + 48 + (lane & 3)*4] = make_uint2(0u, 0u);
    #define HINIT(SV, R, H0_, H1_)                                             \
        { unsigned hpk_;                                                       \
          asm("v_cvt_pk_bf16_f32 %0, %1, %2" : "=v"(hpk_) : "v"(H0_), "v"(H1_)); \
          SV[(quad*4 + (R))*72 + 16 + c] = (unsigned short)hpk_;               \
          SV[(quad*4 + (R))*72 + 32 + c] = (unsigned short)(hpk_ >> 16); }
    HINIT(svA, 0, hA00, hA01); HINIT(svA, 1, hA10, hA11);
    HINIT(svA, 2, hA20, hA21); HINIT(svA, 3, hA30, hA31);
    HINIT(svB, 0, hB00, hB01); HINIT(svB, 1, hB10, hB11);
    HINIT(svB, 2, hB20, hB21); HINIT(svB, 3, hB30, hB31);
    #undef HINIT

    const unsigned short* xrowA = xin + ((size_t)(baseA + (lane >> 2)))*NT*CH + (lane & 3)*4;
    const unsigned short* xrowB = xin + ((size_t)(baseB + (lane >> 2)))*NT*CH + (lane & 3)*4;
    {
        const uint2 xa = *(const uint2*)(xrowA);
        const uint2 xb = *(const uint2*)(xrowB);
        *(uint2*)&svA[(lane >> 2)*72 + (lane & 3)*4] = xa;
        *(uint2*)&svB[(lane >> 2)*72 + (lane & 3)*4] = xb;
    }
    uint2 pA1 = *(const uint2*)(xrowA + 1*CH);   // x(t=1)
    uint2 pA2 = *(const uint2*)(xrowA + 2*CH);   // x(t=2)
    uint2 pB1 = *(const uint2*)(xrowB + 1*CH);
    uint2 pB2 = *(const uint2*)(xrowB + 2*CH);
    __builtin_amdgcn_wave_barrier();

    #define GSTEP(S, A0_, A1_, A2_, A3_, A4_, A5_, A6_, A7_, R, HP0, HP1)      \
        {                                                                      \
            const float rr0 = sig_(A0_[R]);                                    \
            const float rr1 = sig_(A1_[R]);                                    \
            const float zz0 = sig_(A2_[R]);                                    \
            const float zz1 = sig_(A3_[R]);                                    \
            const float aa0 = fmaf(rr0, A6_[R], A4_[R]);                       \
            const float aa1 = fmaf(rr1, A7_[R], A5_[R]);                       \
            const float nn0 = fmaf(2.f, sig_(2.f*aa0), -1.f);                  \
            const float nn1 = fmaf(2.f, sig_(2.f*aa1), -1.f);                  \
            HP0 = fmaf(zz0, HP0 - nn0, nn0);                                   \
            HP1 = fmaf(zz1, HP1 - nn1, nn1);                                   \
            unsigned hpk_;                                                     \
            asm("v_cvt_pk_bf16_f32 %0, %1, %2"                                 \
                : "=v"(hpk_) : "v"(HP0), "v"(HP1));                            \
            S[(quad*4 + (R))*72 + 16 + c] = (unsigned short)hpk_;              \
            S[(quad*4 + (R))*72 + 32 + c] = (unsigned short)(hpk_ >> 16);      \
        }

    #define MFMABLK(A0F, A1F, T0,T1,T2,T3,T4,T5,T6,T7,T8)                      \
        T0 = __builtin_amdgcn_mfma_f32_16x16x32_bf16(A0F, B0a, cb0, 0, 0, 0);  \
        T1 = __builtin_amdgcn_mfma_f32_16x16x32_bf16(A0F, B1a, cb1, 0, 0, 0);  \
        T2 = __builtin_amdgcn_mfma_f32_16x16x32_bf16(A0F, B2a, cb2, 0, 0, 0);  \
        T3 = __builtin_amdgcn_mfma_f32_16x16x32_bf16(A0F, B3a, cb3, 0, 0, 0);  \
        T4 = __builtin_amdgcn_mfma_f32_16x16x32_bf16(A0F, B4a, cb4, 0, 0, 0);  \
        T5 = __builtin_amdgcn_mfma_f32_16x16x32_bf16(A0F, B5a, cb5, 0, 0, 0);  \
        T6 = __builtin_amdgcn_mfma_f32_16x16x32_bf16(A0F, B6a, cb6, 0, 0, 0);  \
        T7 = __builtin_amdgcn_mfma_f32_16x16x32_bf16(A0F, B7a, cb7, 0, 0, 0);  \
        T8 = __builtin_amdgcn_mfma_f32_16x16x32_bf16(A0F, Bfa, cb8, 0, 0, 0);  \
        T0 = __builtin_amdgcn_mfma_f32_16x16x32_bf16(A1F, B0b, T0, 0, 0, 0);   \
        T1 = __builtin_amdgcn_mfma_f32_16x16x32_bf16(A1F, B1b, T1, 0, 0, 0);   \
        T2 = __builtin_amdgcn_mfma_f32_16x16x32_bf16(A1F, B2b, T2, 0, 0, 0);   \
        T3 = __builtin_amdgcn_mfma_f32_16x16x32_bf16(A1F, B3b, T3, 0, 0, 0);   \
        T6 = __builtin_amdgcn_mfma_f32_16x16x32_bf16(A1F, B6b, T6, 0, 0, 0);   \
        T7 = __builtin_amdgcn_mfma_f32_16x16x32_bf16(A1F, B7b, T7, 0, 0, 0);   \
        T8 = __builtin_amdgcn_mfma_f32_16x16x32_bf16(A1F, Bfb, T8, 0, 0, 0);

    for (int t = 0; t < NT; t++) {
        const short8 a0A = *(const short8*)&svA[c*72 + quad*8];
        const short8 a1A = *(const short8*)&svA[c*72 + 32 + quad*8];
        const short8 a0B = *(const short8*)&svB[c*72 + quad*8];
        const short8 a1B = *(const short8*)&svB[c*72 + 32 + quad*8];
        __builtin_amdgcn_wave_barrier();   // pin reads before this iter's writes

        // prefetch x(t+3) for both groups
        const int tn = (t + 3 < NT) ? t + 3 : NT - 1;
        const uint2 fxA = *(const uint2*)(xrowA + (size_t)tn*CH);
        const uint2 fxB = *(const uint2*)(xrowB + (size_t)tn*CH);

        f32x4 aA0, aA1, aA2, aA3, aA4, aA5, aA6, aA7, aA8;
        f32x4 aB0, aB1, aB2, aB3, aB4, aB5, aB6, aB7, aB8;
        MFMABLK(a0A, a1A, aA0,aA1,aA2,aA3,aA4,aA5,aA6,aA7,aA8)
        MFMABLK(a0B, a1B, aB0,aB1,aB2,aB3,aB4,aB5,aB6,aB7,aB8)

        // prob[t-1] for both groups (logits same in every col; c==0 stores)
        if (t > 0 && c == 0) {
            prob[(size_t)(baseA + quad*4 + 0)*NT + (t - 1)] = sig_(aA8[0]);
            prob[(size_t)(baseA + quad*4 + 1)*NT + (t - 1)] = sig_(aA8[1]);
            prob[(size_t)(baseA + quad*4 + 2)*NT + (t - 1)] = sig_(aA8[2]);
            prob[(size_t)(baseA + quad*4 + 3)*NT + (t - 1)] = sig_(aA8[3]);
            prob[(size_t)(baseB + quad*4 + 0)*NT + (t - 1)] = sig_(aB8[0]);
            prob[(size_t)(baseB + quad*4 + 1)*NT + (t - 1)] = sig_(aB8[1]);
            prob[(size_t)(baseB + quad*4 + 2)*NT + (t - 1)] = sig_(aB8[2]);
            prob[(size_t)(baseB + quad*4 + 3)*NT + (t - 1)] = sig_(aB8[3]);
        }

        GSTEP(svA, aA0,aA1,aA2,aA3,aA4,aA5,aA6,aA7, 0, hA00, hA01);
        GSTEP(svA, aA0,aA1,aA2,aA3,aA4,aA5,aA6,aA7, 1, hA10, hA11);
        GSTEP(svA, aA0,aA1,aA2,aA3,aA4,aA5,aA6,aA7, 2, hA20, hA21);
        GSTEP(svA, aA0,aA1,aA2,aA3,aA4,aA5,aA6,aA7, 3, hA30, hA31);
        GSTEP(svB, aB0,aB1,aB2,aB3,aB4,aB5,aB6,aB7, 0, hB00, hB01);
        GSTEP(svB, aB0,aB1,aB2,aB3,aB4,aB5,aB6,aB7, 1, hB10, hB11);
        GSTEP(svB, aB0,aB1,aB2,aB3,aB4,aB5,aB6,aB7, 2, hB20, hB21);
        GSTEP(svB, aB0,aB1,aB2,aB3,aB4,aB5,aB6,aB7, 3, hB30, hB31);

        // stage x(t+1), rotate both prefetch pipelines
        *(uint2*)&svA[(lane >> 2)*72 + (lane & 3)*4] = pA1;
        *(uint2*)&svB[(lane >> 2)*72 + (lane & 3)*4] = pB1;
        pA1 = pA2; pA2 = fxA;
        pB1 = pB2; pB2 = fxB;
        __builtin_amdgcn_wave_barrier();
    }

    // prob for the final step (h_NT in sv)
    {
        const short8 a0A = *(const short8*)&svA[c*72 + quad*8];
        const short8 a1A = *(const short8*)&svA[c*72 + 32 + quad*8];
        const short8 a0B = *(const short8*)&svB[c*72 + quad*8];
        const short8 a1B = *(const short8*)&svB[c*72 + 32 + quad*8];
        f32x4 pA = __builtin_amdgcn_mfma_f32_16x16x32_bf16(a0A, Bfa, cb8, 0, 0, 0);
        pA = __builtin_amdgcn_mfma_f32_16x16x32_bf16(a1A, Bfb, pA, 0, 0, 0);
        f32x4 pB = __builtin_amdgcn_mfma_f32_16x16x32_bf16(a0B, Bfa, cb8, 0, 0, 0);
        pB = __builtin_amdgcn_mfma_f32_16x16x32_bf16(a1B, Bfb, pB, 0, 0, 0);
        if (c == 0) {
            prob[(size_t)(baseA + quad*4 + 0)*NT + (NT - 1)] = sig_(pA[0]);
            prob[(size_t)(baseA + quad*4 + 1)*NT + (NT - 1)] = sig_(pA[1]);
            prob[(size_t)(baseA + quad*4 + 2)*NT + (NT - 1)] = sig_(pA[2]);
            prob[(size_t)(baseA + quad*4 + 3)*NT + (NT - 1)] = sig_(pA[3]);
            prob[(size_t)(baseB + quad*4 + 0)*NT + (NT - 1)] = sig_(pB[0]);
            prob[(size_t)(baseB + quad*4 + 1)*NT + (NT - 1)] = sig_(pB[1]);
            prob[(size_t)(baseB + quad*4 + 2)*NT + (NT - 1)] = sig_(pB[2]);
            prob[(size_t)(baseB + quad*4 + 3)*NT + (NT - 1)] = sig_(pB[3]);
        }
    }

    hout[(size_t)(baseA + quad*4 + 0)*HID + c]      = hA00;
    hout[(size_t)(baseA + quad*4 + 0)*HID + 16 + c] = hA01;
    hout[(size_t)(baseA + quad*4 + 1)*HID + c]      = hA10;
    hout[(size_t)(baseA + quad*4 + 1)*HID + 16 + c] = hA11;
    hout[(size_t)(baseA + quad*4 + 2)*HID + c]      = hA20;
    hout[(size_t)(baseA + quad*4 + 2)*HID + 16 + c] = hA21;
    hout[(size_t)(baseA + quad*4 + 3)*HID + c]      = hA30;
    hout[(size_t)(baseA + quad*4 + 3)*HID + 16 + c] = hA31;
    hout[(size_t)(baseB + quad*4 + 0)*HID + c]      = hB00;
    hout[(size_t)(baseB + quad*4 + 0)*HID + 16 + c] = hB01;
    hout[(size_t)(baseB + quad*4 + 1)*HID + c]      = hB10;
    hout[(size_t)(baseB + quad*4 + 1)*HID + 16 + c] = hB11;
    hout[(size_t)(baseB + quad*4 + 2)*HID + c]      = hB20;
    hout[(size_t)(baseB + quad*4 + 2)*HID + 16 + c] = hB21;
    hout[(size_t)(baseB + quad*4 + 3)*HID + c]      = hB30;
    hout[(size_t)(baseB + quad*4 + 3)*HID + 16 + c] = hB31;
}

// -------------------------------------------------------------------------
extern "C" void kernel_launch(void* const* d_in, const int* in_sizes, int n_in,
                              void* d_out, int out_size, void* d_ws, size_t ws_size,
                              hipStream_t stream)
{
    const float* feat = (const float*)d_in[0];
    const float* h0   = (const float*)d_in[1];
    const float* w1   = (const float*)d_in[2];
    const float* b1   = (const float*)d_in[3];
    const float* a1   = (const float*)d_in[4];
    const float* w2   = (const float*)d_in[5];
    const float* b2   = (const float*)d_in[6];
    const float* a2   = (const float*)d_in[7];
    const float* wih  = (const float*)d_in[8];
    const float* whh  = (const float*)d_in[9];
    const float* bih  = (const float*)d_in[10];
    const float* bhh  = (const float*)d_in[11];
    const float* fcw  = (const float*)d_in[12];
    const float* fcb  = (const float*)d_in[13];

    unsigned short* xbuf = (unsigned short*)d_ws;            // 123.1 MB bf16
    unsigned short* y1   = xbuf + (size_t)NSEQ*NT*CH;        // 123.1 MB bf16 (b,f,t,ch)
    float* prob = (float*)d_out;                             // (B, F, T)
    float* hout = prob + (size_t)NSEQ*NT;                    // (1, NSEQ, 32)

    dim3 c1grid(NB, 121, 2);                                 // 4 f-waves/block
    conv1_kernel<<<c1grid, 256, 0, stream>>>(feat, w1, b1, a1, y1);
    dim3 c2grid(NB, 121, 4);                                 // 4 f x 128 t per block
    conv2_kernel<<<c2grid, 256, 0, stream>>>(y1, w2, b2, a2, xbuf);
    gru_kernel<<<(NSEQ + 31)/32, 64, 0, stream>>>(xbuf, h0, wih, whh, bih, bhh, fcw, fcb, prob, hout);
}

// Round 7
// 768.904 us; speedup vs baseline: 1.2347x; 1.2347x over previous
//
#include <hip/hip_runtime.h>

#define NF 481
#define NT 500
#define CH 16
#define HID 32
#define NB 16
#define NSEQ (NB*NF)   // 7696

typedef __attribute__((ext_vector_type(8))) short short8;
typedef __attribute__((ext_vector_type(4))) float f32x4;

// fast sigmoid — v_rcp instead of correctly-rounded divide (R10 win)
__device__ __forceinline__ float sig_(float v) {
    return __builtin_amdgcn_rcpf(1.0f + __expf(-v));
}

__device__ __forceinline__ unsigned short f2bf(float f) {
    unsigned u = __float_as_uint(f);
    u = (u + 0x7fffu + ((u >> 16) & 1u)) >> 16;   // RNE
    return (unsigned short)u;
}
__device__ __forceinline__ unsigned int pk2(float a, float b) {
    return (unsigned int)f2bf(a) | ((unsigned int)f2bf(b) << 16);
}
__device__ __forceinline__ float bf2f(short s) {
    return __uint_as_float(((unsigned)(unsigned short)s) << 16);
}
__device__ __forceinline__ float4 prelu4(float4 v, float a) {
    v.x = (v.x >= 0.f) ? v.x : a*v.x;
    v.y = (v.y >= 0.f) ? v.y : a*v.y;
    v.z = (v.z >= 0.f) ? v.z : a*v.z;
    v.w = (v.w >= 0.f) ? v.w : a*v.w;
    return v;
}

#define FMA4(Q, W, V)                     \
    Q.x = fmaf((W), (V).x, Q.x);          \
    Q.y = fmaf((W), (V).y, Q.y);          \
    Q.z = fmaf((W), (V).z, Q.z);          \
    Q.w = fmaf((W), (V).w, Q.w)

// -------------------------------------------------------------------------
// Pass 1: conv1(4->16,k9,p4) + PReLU -> y1 (b,f,t,ch) bf16.
// R7: feat tile (12 f-rows x 4 d x 256 t, 48KB) staged in LDS ONCE per
// block — kills the 9x redundant global halo reads and all per-tap bounds
// branches (halo rows pre-zeroed).  FMA pyramid itself unchanged.
// -------------------------------------------------------------------------
#define P1TAP(D, K1)                                                           \
    {                                                                          \
        const float4 v = *(const float4*)&flds[((size_t)((K1) + wv)*4 + (D))*256 + tlc]; \
        FMA4(q0,  w1[ 0*36 + (D)*9 + (K1)], v);                                \
        FMA4(q1,  w1[ 1*36 + (D)*9 + (K1)], v);                                \
        FMA4(q2,  w1[ 2*36 + (D)*9 + (K1)], v);                                \
        FMA4(q3,  w1[ 3*36 + (D)*9 + (K1)], v);                                \
        FMA4(q4,  w1[ 4*36 + (D)*9 + (K1)], v);                                \
        FMA4(q5,  w1[ 5*36 + (D)*9 + (K1)], v);                                \
        FMA4(q6,  w1[ 6*36 + (D)*9 + (K1)], v);                                \
        FMA4(q7,  w1[ 7*36 + (D)*9 + (K1)], v);                                \
        FMA4(q8,  w1[ 8*36 + (D)*9 + (K1)], v);                                \
        FMA4(q9,  w1[ 9*36 + (D)*9 + (K1)], v);                                \
        FMA4(q10, w1[10*36 + (D)*9 + (K1)], v);                                \
        FMA4(q11, w1[11*36 + (D)*9 + (K1)], v);                                \
        FMA4(q12, w1[12*36 + (D)*9 + (K1)], v);                                \
        FMA4(q13, w1[13*36 + (D)*9 + (K1)], v);                                \
        FMA4(q14, w1[14*36 + (D)*9 + (K1)], v);                                \
        FMA4(q15, w1[15*36 + (D)*9 + (K1)], v);                                \
    }

#define STX(OP, E, COMP)                                                       \
    *(uint4*)((OP) + (E)*CH) = make_uint4(                                     \
        pk2(q0.COMP, q1.COMP),  pk2(q2.COMP, q3.COMP),                         \
        pk2(q4.COMP, q5.COMP),  pk2(q6.COMP, q7.COMP));                        \
    *(uint4*)((OP) + (E)*CH + 8) = make_uint4(                                 \
        pk2(q8.COMP, q9.COMP),  pk2(q10.COMP, q11.COMP),                       \
        pk2(q12.COMP, q13.COMP), pk2(q14.COMP, q15.COMP))

__global__ __launch_bounds__(256) void conv1_kernel(
    const float* __restrict__ feat,
    const float* __restrict__ w1, const float* __restrict__ b1, const float* __restrict__ a1p,
    unsigned short* __restrict__ y1)          // (b, f, t, ch) bf16
{
    __shared__ float flds[48*256];           // 48 KB: [(row12)*4+d][t256]
    const int b    = blockIdx.x;
    const int f0   = blockIdx.y*4;
    const int tg   = blockIdx.z*256;
    const int wv   = threadIdx.x >> 6;       // wave id: f = f0 + wv
    const int lane = threadIdx.x & 63;
    const int f    = f0 + wv;

    // ---- stage feat tile: rows f0-4 .. f0+7 (zero outside), all 4 deltas
    {
        const int ts = ((tg + lane*4) <= NT-4) ? (tg + lane*4) : (NT-4);
        #pragma unroll
        for (int i = 0; i < 12; i++) {
            const int seg = i*4 + wv;        // 0..47
            const int row = seg >> 2;        // 0..11
            const int d   = seg & 3;
            const int gf  = f0 - 4 + row;
            float4 v = make_float4(0.f, 0.f, 0.f, 0.f);
            if (gf >= 0 && gf < NF)
                v = *(const float4*)(feat + ((size_t)(b*4 + d)*NF + gf)*NT + ts);
            *(float4*)&flds[(size_t)seg*256 + lane*4] = v;
        }
    }
    __syncthreads();
    if (f >= NF) return;

    const int gt0 = tg + lane*4;
    const int tlc = (gt0 <= NT-4) ? lane*4 : (NT-4) - tg;   // local t of clamped read
    const float al1 = a1p[0];

    float4 q0  = make_float4(b1[0],b1[0],b1[0],b1[0]);
    float4 q1  = make_float4(b1[1],b1[1],b1[1],b1[1]);
    float4 q2  = make_float4(b1[2],b1[2],b1[2],b1[2]);
    float4 q3  = make_float4(b1[3],b1[3],b1[3],b1[3]);
    float4 q4  = make_float4(b1[4],b1[4],b1[4],b1[4]);
    float4 q5  = make_float4(b1[5],b1[5],b1[5],b1[5]);
    float4 q6  = make_float4(b1[6],b1[6],b1[6],b1[6]);
    float4 q7  = make_float4(b1[7],b1[7],b1[7],b1[7]);
    float4 q8  = make_float4(b1[8],b1[8],b1[8],b1[8]);
    float4 q9  = make_float4(b1[9],b1[9],b1[9],b1[9]);
    float4 q10 = make_float4(b1[10],b1[10],b1[10],b1[10]);
    float4 q11 = make_float4(b1[11],b1[11],b1[11],b1[11]);
    float4 q12 = make_float4(b1[12],b1[12],b1[12],b1[12]);
    float4 q13 = make_float4(b1[13],b1[13],b1[13],b1[13]);
    float4 q14 = make_float4(b1[14],b1[14],b1[14],b1[14]);
    float4 q15 = make_float4(b1[15],b1[15],b1[15],b1[15]);

    #pragma unroll
    for (int d = 0; d < 4; d++) {
        P1TAP(d, 0); P1TAP(d, 1); P1TAP(d, 2); P1TAP(d, 3); P1TAP(d, 4);
        P1TAP(d, 5); P1TAP(d, 6); P1TAP(d, 7); P1TAP(d, 8);
    }

    if (gt0 < NT) {
        q0  = prelu4(q0,  al1); q1  = prelu4(q1,  al1);
        q2  = prelu4(q2,  al1); q3  = prelu4(q3,  al1);
        q4  = prelu4(q4,  al1); q5  = prelu4(q5,  al1);
        q6  = prelu4(q6,  al1); q7  = prelu4(q7,  al1);
        q8  = prelu4(q8,  al1); q9  = prelu4(q9,  al1);
        q10 = prelu4(q10, al1); q11 = prelu4(q11, al1);
        q12 = prelu4(q12, al1); q13 = prelu4(q13, al1);
        q14 = prelu4(q14, al1); q15 = prelu4(q15, al1);
        unsigned short* op = y1 + ((size_t)(b*NF + f)*NT + gt0)*CH;
        STX(op, 0, x); STX(op, 1, y); STX(op, 2, z); STX(op, 3, w);
    }
}

// -------------------------------------------------------------------------
// Pass 2: conv2(16->16,k5,p2) via MFMA + PReLU -> x (n,t,16).  (unchanged R5)
// -------------------------------------------------------------------------
__global__ __launch_bounds__(256) void conv2_kernel(
    const unsigned short* __restrict__ y1,    // (b, f, t, ch) bf16
    const float* __restrict__ w2, const float* __restrict__ b2, const float* __restrict__ a2p,
    unsigned short* __restrict__ xout)
{
    __shared__ unsigned short ylds[8*128*24];    // 48 KB: [row8][t128][ch16+pad8]
    const int b    = blockIdx.x;
    const int f0   = blockIdx.y * 4;
    const int tg   = blockIdx.z * 128;
    const int tid  = threadIdx.x;
    const int wid  = tid >> 6;
    const int lane = tid & 63;

    #pragma unroll
    for (int i = 0; i < 8; i++) {
        const int idx  = tid + i*256;        // 0..2047
        const int row  = idx >> 8;           // 0..7
        const int tt   = (idx >> 1) & 127;
        const int half = idx & 1;
        const int fr   = f0 - 2 + row;
        const int gt   = tg + tt;
        uint4 v = make_uint4(0u, 0u, 0u, 0u);
        if (fr >= 0 && fr < NF && gt < NT)
            v = *(const uint4*)(y1 + ((size_t)(b*NF + fr)*NT + gt)*CH + half*8);
        *(uint4*)&ylds[(row*128 + tt)*24 + half*8] = v;
    }
    __syncthreads();

    const int c    = lane & 15;
    const int quad = lane >> 4;
    const int f    = f0 + wid;
    if (f < NF) {
        const float al2 = a2p[0];
        short8 Bh0, Bh1, Bh2, Bl0, Bl1, Bl2;
        #define MKB2(BH, BL, Q)                                                \
            { _Pragma("unroll") for (int j = 0; j < 8; j++) {                  \
                const int ci = (quad & 1)*8 + j;                               \
                const int kk = 2*(Q) + (quad >> 1);                            \
                float w = 0.f;                                                 \
                if (kk < 5) w = w2[c*80 + ci*5 + kk];                          \
                const unsigned short hb = f2bf(w);                             \
                const float hf = bf2f((short)hb);                              \
                BH[j] = (short)hb;                                             \
                BL[j] = (short)f2bf(w - hf); } }
        MKB2(Bh0, Bl0, 0); MKB2(Bh1, Bl1, 1); MKB2(Bh2, Bl2, 2);
        #undef MKB2

        const f32x4 cb = {b2[c], b2[c], b2[c], b2[c]};
        const int ci0 = (quad & 1)*8;
        const int r0  = wid + (quad >> 1);
        unsigned short* xo = xout + ((size_t)(b*NF + f)*NT)*CH + c;

        #pragma unroll
        for (int ti = 0; ti < 8; ti++) {
            const int t = ti*16 + c;
            const int rl2 = (r0 + 4 > 7) ? 7 : (r0 + 4);
            const short8 a0 = *(const short8*)&ylds[((r0    )*128 + t)*24 + ci0];
            const short8 a1 = *(const short8*)&ylds[((r0 + 2)*128 + t)*24 + ci0];
            const short8 a2 = *(const short8*)&ylds[((rl2   )*128 + t)*24 + ci0];
            f32x4 acc = cb;
            acc = __builtin_amdgcn_mfma_f32_16x16x32_bf16(a0, Bl0, acc, 0, 0, 0);
            acc = __builtin_amdgcn_mfma_f32_16x16x32_bf16(a1, Bl1, acc, 0, 0, 0);
            acc = __builtin_amdgcn_mfma_f32_16x16x32_bf16(a2, Bl2, acc, 0, 0, 0);
            acc = __builtin_amdgcn_mfma_f32_16x16x32_bf16(a0, Bh0, acc, 0, 0, 0);
            acc = __builtin_amdgcn_mfma_f32_16x16x32_bf16(a1, Bh1, acc, 0, 0, 0);
            acc = __builtin_amdgcn_mfma_f32_16x16x32_bf16(a2, Bh2, acc, 0, 0, 0);
            #pragma unroll
            for (int r = 0; r < 4; r++) {
                const int tt = tg + ti*16 + quad*4 + r;
                if (tt < NT) {
                    float v = acc[r];
                    v = (v >= 0.f) ? v : al2*v;
                    xo[(size_t)tt*CH] = f2bf(v);
                }
            }
        }
    }
}

// -------------------------------------------------------------------------
// GRU via MFMA — exact R5 kernel (proven 356 us).  R6's in-wave dual
// pipeline showed the step is ISSUE-bound (marginal cost of duplicate work
// ~= full serial cost), so only instruction-count reduction helps; the 24
// sigmoids/step are algorithmically minimal.  Reverted verbatim.
// -------------------------------------------------------------------------
__global__ __launch_bounds__(64) void gru_kernel(
    const unsigned short* __restrict__ xin,  // (NSEQ, NT, 16) bf16
    const float* __restrict__ h0,    // (NSEQ, 32)
    const float* __restrict__ w_ih,  // (96, 16)
    const float* __restrict__ w_hh,  // (96, 32)
    const float* __restrict__ b_ih, const float* __restrict__ b_hh,
    const float* __restrict__ fc_w, const float* __restrict__ fc_b,
    float* __restrict__ prob,        // (NSEQ, NT)
    float* __restrict__ hout)        // (NSEQ, 32)
{
    __shared__ unsigned short sv[16*72];     // [seq][x16|h32|pad16] bf16
    const int lane = threadIdx.x & 63;
    const int c    = lane & 15;
    const int quad = lane >> 4;
    const int base = blockIdx.x * 16;        // 481 blocks x 16 seq

    #define MKB(DST, G, CK)                                                    \
        { _Pragma("unroll") for (int j = 0; j < 8; j++) {                      \
            const int k = (CK)*32 + quad*8 + j;                                \
            const int g = (G);                                                 \
            float wv_;                                                         \
            if (g < 64)      wv_ = (k < 16) ? w_ih[g*16 + k]                   \
                                  : (k < 48) ? w_hh[g*32 + k - 16] : 0.f;      \
            else if (g < 96) wv_ = (k < 16) ? w_ih[g*16 + k] : 0.f;            \
            else             wv_ = (k >= 16 && k < 48)                         \
                                  ? w_hh[(g-32)*32 + k - 16] : 0.f;            \
            DST[j] = (short)f2bf(wv_); } }

    short8 B0a, B0b, B1a, B1b, B2a, B2b, B3a, B3b, B4a, B5a, B6a, B6b, B7a, B7b;
    MKB(B0a,       c, 0); MKB(B0b,       c, 1);   // r  units 0..15
    MKB(B1a,  16 + c, 0); MKB(B1b,  16 + c, 1);   // r  units 16..31
    MKB(B2a,  32 + c, 0); MKB(B2b,  32 + c, 1);   // z
    MKB(B3a,  48 + c, 0); MKB(B3b,  48 + c, 1);
    MKB(B4a,  64 + c, 0);                          // xn (chunk1 all-zero)
    MKB(B5a,  80 + c, 0);
    MKB(B6a,  96 + c, 0); MKB(B6b,  96 + c, 1);   // hn
    MKB(B7a, 112 + c, 0); MKB(B7b, 112 + c, 1);

    // FC fragment: same value in every col; k=16..47 <-> h units 0..31
    short8 Bfa, Bfb;
    { _Pragma("unroll") for (int j = 0; j < 8; j++) {
        const int k0 = quad*8 + j;
        Bfa[j] = (short)((k0 >= 16) ? f2bf(fc_w[k0 - 16]) : 0);
        const int k1 = 32 + quad*8 + j;
        Bfb[j] = (short)((k1 < 48) ? f2bf(fc_w[k1 - 16]) : 0);
    } }

    const float bi0 = b_ih[c]      + b_hh[c];
    const float bi1 = b_ih[16 + c] + b_hh[16 + c];
    const float bi2 = b_ih[32 + c] + b_hh[32 + c];
    const float bi3 = b_ih[48 + c] + b_hh[48 + c];
    const float bi4 = b_ih[64 + c];
    const float bi5 = b_ih[80 + c];
    const float bi6 = b_hh[64 + c];
    const float bi7 = b_hh[80 + c];
    const float fb = fc_b[0];

    // loop-invariant bias vectors fed straight into the first MFMA as C
    const f32x4 cb0 = {bi0, bi0, bi0, bi0};
    const f32x4 cb1 = {bi1, bi1, bi1, bi1};
    const f32x4 cb2 = {bi2, bi2, bi2, bi2};
    const f32x4 cb3 = {bi3, bi3, bi3, bi3};
    const f32x4 cb4 = {bi4, bi4, bi4, bi4};
    const f32x4 cb5 = {bi5, bi5, bi5, bi5};
    const f32x4 cb6 = {bi6, bi6, bi6, bi6};
    const f32x4 cb7 = {bi7, bi7, bi7, bi7};
    const f32x4 cb8 = {fb, fb, fb, fb};

    float hp00 = h0[(size_t)(base + quad*4 + 0)*HID + c];
    float hp01 = h0[(size_t)(base + quad*4 + 0)*HID + 16 + c];
    float hp10 = h0[(size_t)(base + quad*4 + 1)*HID + c];
    float hp11 = h0[(size_t)(base + quad*4 + 1)*HID + 16 + c];
    float hp20 = h0[(size_t)(base + quad*4 + 2)*HID + c];
    float hp21 = h0[(size_t)(base + quad*4 + 2)*HID + 16 + c];
    float hp30 = h0[(size_t)(base + quad*4 + 3)*HID + c];
    float hp31 = h0[(size_t)(base + quad*4 + 3)*HID + 16 + c];

    // ---- init LDS v-buffer ----
    *(uint2*)&sv[(lane >> 2)*72 + 48 + (lane & 3)*4] = make_uint2(0u, 0u);
    sv[(quad*4 + 0)*72 + 16 + c] = f2bf(hp00);  sv[(quad*4 + 0)*72 + 32 + c] = f2bf(hp01);
    sv[(quad*4 + 1)*72 + 16 + c] = f2bf(hp10);  sv[(quad*4 + 1)*72 + 32 + c] = f2bf(hp11);
    sv[(quad*4 + 2)*72 + 16 + c] = f2bf(hp20);  sv[(quad*4 + 2)*72 + 32 + c] = f2bf(hp21);
    sv[(quad*4 + 3)*72 + 16 + c] = f2bf(hp30);  sv[(quad*4 + 3)*72 + 32 + c] = f2bf(hp31);
    const unsigned short* xrow = xin + ((size_t)(base + (lane >> 2)))*NT*CH + (lane & 3)*4;
    {
        const uint2 x0v = *(const uint2*)(xrow);
        *(uint2*)&sv[(lane >> 2)*72 + (lane & 3)*4] = x0v;
    }
    uint2 nxA = *(const uint2*)(xrow + 1*CH);   // x(t=1)
    uint2 nxB = *(const uint2*)(xrow + 2*CH);   // x(t=2)
    __builtin_amdgcn_wave_barrier();

    #define GSTEP(R, HP0, HP1)                                                 \
        {                                                                      \
            const float rr0 = sig_(acc0[R]);                                   \
            const float rr1 = sig_(acc1[R]);                                   \
            const float zz0 = sig_(acc2[R]);                                   \
            const float zz1 = sig_(acc3[R]);                                   \
            const float aa0 = fmaf(rr0, acc6[R], acc4[R]);                     \
            const float aa1 = fmaf(rr1, acc7[R], acc5[R]);                     \
            const float nn0 = fmaf(2.f, sig_(2.f*aa0), -1.f);                  \
            const float nn1 = fmaf(2.f, sig_(2.f*aa1), -1.f);                  \
            HP0 = fmaf(zz0, HP0 - nn0, nn0);                                   \
            HP1 = fmaf(zz1, HP1 - nn1, nn1);                                   \
            unsigned hpk_;                                                     \
            asm("v_cvt_pk_bf16_f32 %0, %1, %2"                                 \
                : "=v"(hpk_) : "v"(HP0), "v"(HP1));                            \
            sv[(quad*4 + (R))*72 + 16 + c] = (unsigned short)hpk_;             \
            sv[(quad*4 + (R))*72 + 32 + c] = (unsigned short)(hpk_ >> 16);     \
        }

    for (int t = 0; t < NT; t++) {
        const short8 a0  = *(const short8*)&sv[c*72 + quad*8];        // k 0..31
        const short8 a1  = *(const short8*)&sv[c*72 + 32 + quad*8];   // k 32..63
        __builtin_amdgcn_wave_barrier();   // pin reads before this iter's writes

        // prefetch x(t+3)
        const int tn = (t + 3 < NT) ? t + 3 : NT - 1;
        const uint2 fx = *(const uint2*)(xrow + (size_t)tn*CH);

        f32x4 acc0 = __builtin_amdgcn_mfma_f32_16x16x32_bf16(a0, B0a, cb0, 0, 0, 0);
        f32x4 acc1 = __builtin_amdgcn_mfma_f32_16x16x32_bf16(a0, B1a, cb1, 0, 0, 0);
        f32x4 acc2 = __builtin_amdgcn_mfma_f32_16x16x32_bf16(a0, B2a, cb2, 0, 0, 0);
        f32x4 acc3 = __builtin_amdgcn_mfma_f32_16x16x32_bf16(a0, B3a, cb3, 0, 0, 0);
        f32x4 acc4 = __builtin_amdgcn_mfma_f32_16x16x32_bf16(a0, B4a, cb4, 0, 0, 0);
        f32x4 acc5 = __builtin_amdgcn_mfma_f32_16x16x32_bf16(a0, B5a, cb5, 0, 0, 0);
        f32x4 acc6 = __builtin_amdgcn_mfma_f32_16x16x32_bf16(a0, B6a, cb6, 0, 0, 0);
        f32x4 acc7 = __builtin_amdgcn_mfma_f32_16x16x32_bf16(a0, B7a, cb7, 0, 0, 0);
        f32x4 acc8 = __builtin_amdgcn_mfma_f32_16x16x32_bf16(a0, Bfa, cb8, 0, 0, 0);
        acc0 = __builtin_amdgcn_mfma_f32_16x16x32_bf16(a1, B0b, acc0, 0, 0, 0);
        acc1 = __builtin_amdgcn_mfma_f32_16x16x32_bf16(a1, B1b, acc1, 0, 0, 0);
        acc2 = __builtin_amdgcn_mfma_f32_16x16x32_bf16(a1, B2b, acc2, 0, 0, 0);
        acc3 = __builtin_amdgcn_mfma_f32_16x16x32_bf16(a1, B3b, acc3, 0, 0, 0);
        acc6 = __builtin_amdgcn_mfma_f32_16x16x32_bf16(a1, B6b, acc6, 0, 0, 0);
        acc7 = __builtin_amdgcn_mfma_f32_16x16x32_bf16(a1, B7b, acc7, 0, 0, 0);
        acc8 = __builtin_amdgcn_mfma_f32_16x16x32_bf16(a1, Bfb, acc8, 0, 0, 0);

        // prob[t-1]: acc8[R] = logit for seq quad*4+R (same in every col)
        if (t > 0 && c == 0) {
            prob[(size_t)(base + quad*4 + 0)*NT + (t - 1)] = sig_(acc8[0]);
            prob[(size_t)(base + quad*4 + 1)*NT + (t - 1)] = sig_(acc8[1]);
            prob[(size_t)(base + quad*4 + 2)*NT + (t - 1)] = sig_(acc8[2]);
            prob[(size_t)(base + quad*4 + 3)*NT + (t - 1)] = sig_(acc8[3]);
        }

        GSTEP(0, hp00, hp01);
        GSTEP(1, hp10, hp11);
        GSTEP(2, hp20, hp21);
        GSTEP(3, hp30, hp31);

        // stage x(t+1), rotate prefetch pipeline
        *(uint2*)&sv[(lane >> 2)*72 + (lane & 3)*4] = nxA;
        nxA = nxB; nxB = fx;
        __builtin_amdgcn_wave_barrier();
    }

    // prob for the final step (h_NT is in sv)
    {
        const short8 a0  = *(const short8*)&sv[c*72 + quad*8];
        const short8 a1  = *(const short8*)&sv[c*72 + 32 + quad*8];
        f32x4 acc8 = __builtin_amdgcn_mfma_f32_16x16x32_bf16(a0, Bfa, cb8, 0, 0, 0);
        acc8 = __builtin_amdgcn_mfma_f32_16x16x32_bf16(a1, Bfb, acc8, 0, 0, 0);
        if (c == 0) {
            prob[(size_t)(base + quad*4 + 0)*NT + (NT - 1)] = sig_(acc8[0]);
            prob[(size_t)(base + quad*4 + 1)*NT + (NT - 1)] = sig_(acc8[1]);
            prob[(size_t)(base + quad*4 + 2)*NT + (NT - 1)] = sig_(acc8[2]);
            prob[(size_t)(base + quad*4 + 3)*NT + (NT - 1)] = sig_(acc8[3]);
        }
    }

    hout[(size_t)(base + quad*4 + 0)*HID + c]      = hp00;
    hout[(size_t)(base + quad*4 + 0)*HID + 16 + c] = hp01;
    hout[(size_t)(base + quad*4 + 1)*HID + c]      = hp10;
    hout[(size_t)(base + quad*4 + 1)*HID + 16 + c] = hp11;
    hout[(size_t)(base + quad*4 + 2)*HID + c]      = hp20;
    hout[(size_t)(base + quad*4 + 2)*HID + 16 + c] = hp21;
    hout[(size_t)(base + quad*4 + 3)*HID + c]      = hp30;
    hout[(size_t)(base + quad*4 + 3)*HID + 16 + c] = hp31;
}

// -------------------------------------------------------------------------
extern "C" void kernel_launch(void* const* d_in, const int* in_sizes, int n_in,
                              void* d_out, int out_size, void* d_ws, size_t ws_size,
                              hipStream_t stream)
{
    const float* feat = (const float*)d_in[0];
    const float* h0   = (const float*)d_in[1];
    const float* w1   = (const float*)d_in[2];
    const float* b1   = (const float*)d_in[3];
    const float* a1   = (const float*)d_in[4];
    const float* w2   = (const float*)d_in[5];
    const float* b2   = (const float*)d_in[6];
    const float* a2   = (const float*)d_in[7];
    const float* wih  = (const float*)d_in[8];
    const float* whh  = (const float*)d_in[9];
    const float* bih  = (const float*)d_in[10];
    const float* bhh  = (const float*)d_in[11];
    const float* fcw  = (const float*)d_in[12];
    const float* fcb  = (const float*)d_in[13];

    unsigned short* xbuf = (unsigned short*)d_ws;            // 123.1 MB bf16
    unsigned short* y1   = xbuf + (size_t)NSEQ*NT*CH;        // 123.1 MB bf16 (b,f,t,ch)
    float* prob = (float*)d_out;                             // (B, F, T)
    float* hout = prob + (size_t)NSEQ*NT;                    // (1, NSEQ, 32)

    dim3 c1grid(NB, 121, 2);                                 // 4 f-waves x 256 t
    conv1_kernel<<<c1grid, 256, 0, stream>>>(feat, w1, b1, a1, y1);
    dim3 c2grid(NB, 121, 4);                                 // 4 f x 128 t per block
    conv2_kernel<<<c2grid, 256, 0, stream>>>(y1, w2, b2, a2, xbuf);
    gru_kernel<<<NSEQ/16, 64, 0, stream>>>(xbuf, h0, wih, whh, bih, bhh, fcw, fcb, prob, hout);
}

// Round 8
// 689.965 us; speedup vs baseline: 1.3760x; 1.1144x over previous
//
#include <hip/hip_runtime.h>

#define NF 481
#define NT 500
#define CH 16
#define HID 32
#define NB 16
#define NSEQ (NB*NF)   // 7696

typedef __attribute__((ext_vector_type(8))) short short8;
typedef __attribute__((ext_vector_type(4))) float f32x4;

// fast sigmoid — v_rcp instead of correctly-rounded divide (R10 win)
__device__ __forceinline__ float sig_(float v) {
    return __builtin_amdgcn_rcpf(1.0f + __expf(-v));
}
// sigmoid for PRE-SCALED logits: v = log2e * x  ->  1/(1+2^-v).
// v_exp_f32 with free neg input modifier; saves the mul of __expf.
__device__ __forceinline__ float sige_(float v) {
    float e;
    asm("v_exp_f32 %0, -%1" : "=v"(e) : "v"(v));
    return __builtin_amdgcn_rcpf(1.0f + e);
}

__device__ __forceinline__ unsigned short f2bf(float f) {
    unsigned u = __float_as_uint(f);
    u = (u + 0x7fffu + ((u >> 16) & 1u)) >> 16;   // RNE
    return (unsigned short)u;
}
__device__ __forceinline__ unsigned int pk2(float a, float b) {
    return (unsigned int)f2bf(a) | ((unsigned int)f2bf(b) << 16);
}
__device__ __forceinline__ float bf2f(short s) {
    return __uint_as_float(((unsigned)(unsigned short)s) << 16);
}
__device__ __forceinline__ float4 prelu4(float4 v, float a) {
    v.x = (v.x >= 0.f) ? v.x : a*v.x;
    v.y = (v.y >= 0.f) ? v.y : a*v.y;
    v.z = (v.z >= 0.f) ? v.z : a*v.z;
    v.w = (v.w >= 0.f) ? v.w : a*v.w;
    return v;
}

#define FMA4(Q, W, V)                     \
    Q.x = fmaf((W), (V).x, Q.x);          \
    Q.y = fmaf((W), (V).y, Q.y);          \
    Q.z = fmaf((W), (V).z, Q.z);          \
    Q.w = fmaf((W), (V).w, Q.w)

// -------------------------------------------------------------------------
// Pass 1: conv1(4->16,k9,p4) + PReLU -> y1 (b,f,t,ch) bf16.
// R8: channels split across 2 waves (block = 2 f x 2 ch-halves).  Per-wave
// FMA issue halves, wave count doubles, VGPR ~halves -> more resident waves
// to hide the tap-load latency (R7 showed the loads are L1-hot; the gap vs
// the 29us issue floor is latency exposure, not bandwidth).
// -------------------------------------------------------------------------
#define P1TAP(D, K1)                                                           \
    {                                                                          \
        const int gf = f + (K1) - 4;                                           \
        if (gf >= 0 && gf < NF) {                                              \
            const float4 v = *(const float4*)(feat +                           \
                ((size_t)(b*4 + (D))*NF + gf)*NT + tc0);                       \
            FMA4(q0, w1h[0*36 + (D)*9 + (K1)], v);                             \
            FMA4(q1, w1h[1*36 + (D)*9 + (K1)], v);                             \
            FMA4(q2, w1h[2*36 + (D)*9 + (K1)], v);                             \
            FMA4(q3, w1h[3*36 + (D)*9 + (K1)], v);                             \
            FMA4(q4, w1h[4*36 + (D)*9 + (K1)], v);                             \
            FMA4(q5, w1h[5*36 + (D)*9 + (K1)], v);                             \
            FMA4(q6, w1h[6*36 + (D)*9 + (K1)], v);                             \
            FMA4(q7, w1h[7*36 + (D)*9 + (K1)], v);                             \
        }                                                                      \
    }

#define STX8(E, COMP)                                                          \
    *(uint4*)(op + (E)*CH) = make_uint4(                                       \
        pk2(q0.COMP, q1.COMP),  pk2(q2.COMP, q3.COMP),                         \
        pk2(q4.COMP, q5.COMP),  pk2(q6.COMP, q7.COMP));

__global__ __launch_bounds__(256) void conv1_kernel(
    const float* __restrict__ feat,
    const float* __restrict__ w1, const float* __restrict__ b1, const float* __restrict__ a1p,
    unsigned short* __restrict__ y1)          // (b, f, t, ch) bf16
{
    const int b    = blockIdx.x;
    const int wv   = threadIdx.x >> 6;
    const int lane = threadIdx.x & 63;
    const int f    = blockIdx.y*2 + (wv >> 1);
    const int half = wv & 1;                  // channels half*8 .. half*8+7
    if (f >= NF) return;
    const int gt0  = blockIdx.z*256 + lane*4;
    const int tc0  = (gt0 <= NT-4) ? gt0 : (NT-4);
    const float al1 = a1p[0];
    const float* w1h = w1 + half*8*36;
    const float* b1h = b1 + half*8;

    float4 q0 = make_float4(b1h[0],b1h[0],b1h[0],b1h[0]);
    float4 q1 = make_float4(b1h[1],b1h[1],b1h[1],b1h[1]);
    float4 q2 = make_float4(b1h[2],b1h[2],b1h[2],b1h[2]);
    float4 q3 = make_float4(b1h[3],b1h[3],b1h[3],b1h[3]);
    float4 q4 = make_float4(b1h[4],b1h[4],b1h[4],b1h[4]);
    float4 q5 = make_float4(b1h[5],b1h[5],b1h[5],b1h[5]);
    float4 q6 = make_float4(b1h[6],b1h[6],b1h[6],b1h[6]);
    float4 q7 = make_float4(b1h[7],b1h[7],b1h[7],b1h[7]);

    #pragma unroll
    for (int d = 0; d < 4; d++) {
        P1TAP(d, 0); P1TAP(d, 1); P1TAP(d, 2); P1TAP(d, 3); P1TAP(d, 4);
        P1TAP(d, 5); P1TAP(d, 6); P1TAP(d, 7); P1TAP(d, 8);
    }

    if (gt0 < NT) {
        q0 = prelu4(q0, al1); q1 = prelu4(q1, al1);
        q2 = prelu4(q2, al1); q3 = prelu4(q3, al1);
        q4 = prelu4(q4, al1); q5 = prelu4(q5, al1);
        q6 = prelu4(q6, al1); q7 = prelu4(q7, al1);
        unsigned short* op = y1 + ((size_t)(b*NF + f)*NT + gt0)*CH + half*8;
        STX8(0, x); STX8(1, y); STX8(2, z); STX8(3, w);
    }
}

// -------------------------------------------------------------------------
// Pass 2: conv2(16->16,k5,p2) via MFMA + PReLU -> x (n,t,16).  (unchanged R5)
// -------------------------------------------------------------------------
__global__ __launch_bounds__(256) void conv2_kernel(
    const unsigned short* __restrict__ y1,    // (b, f, t, ch) bf16
    const float* __restrict__ w2, const float* __restrict__ b2, const float* __restrict__ a2p,
    unsigned short* __restrict__ xout)
{
    __shared__ unsigned short ylds[8*128*24];    // 48 KB: [row8][t128][ch16+pad8]
    const int b    = blockIdx.x;
    const int f0   = blockIdx.y * 4;
    const int tg   = blockIdx.z * 128;
    const int tid  = threadIdx.x;
    const int wid  = tid >> 6;
    const int lane = tid & 63;

    #pragma unroll
    for (int i = 0; i < 8; i++) {
        const int idx  = tid + i*256;        // 0..2047
        const int row  = idx >> 8;           // 0..7
        const int tt   = (idx >> 1) & 127;
        const int half = idx & 1;
        const int fr   = f0 - 2 + row;
        const int gt   = tg + tt;
        uint4 v = make_uint4(0u, 0u, 0u, 0u);
        if (fr >= 0 && fr < NF && gt < NT)
            v = *(const uint4*)(y1 + ((size_t)(b*NF + fr)*NT + gt)*CH + half*8);
        *(uint4*)&ylds[(row*128 + tt)*24 + half*8] = v;
    }
    __syncthreads();

    const int c    = lane & 15;
    const int quad = lane >> 4;
    const int f    = f0 + wid;
    if (f < NF) {
        const float al2 = a2p[0];
        short8 Bh0, Bh1, Bh2, Bl0, Bl1, Bl2;
        #define MKB2(BH, BL, Q)                                                \
            { _Pragma("unroll") for (int j = 0; j < 8; j++) {                  \
                const int ci = (quad & 1)*8 + j;                               \
                const int kk = 2*(Q) + (quad >> 1);                            \
                float w = 0.f;                                                 \
                if (kk < 5) w = w2[c*80 + ci*5 + kk];                          \
                const unsigned short hb = f2bf(w);                             \
                const float hf = bf2f((short)hb);                              \
                BH[j] = (short)hb;                                             \
                BL[j] = (short)f2bf(w - hf); } }
        MKB2(Bh0, Bl0, 0); MKB2(Bh1, Bl1, 1); MKB2(Bh2, Bl2, 2);
        #undef MKB2

        const f32x4 cb = {b2[c], b2[c], b2[c], b2[c]};
        const int ci0 = (quad & 1)*8;
        const int r0  = wid + (quad >> 1);
        unsigned short* xo = xout + ((size_t)(b*NF + f)*NT)*CH + c;

        #pragma unroll
        for (int ti = 0; ti < 8; ti++) {
            const int t = ti*16 + c;
            const int rl2 = (r0 + 4 > 7) ? 7 : (r0 + 4);
            const short8 a0 = *(const short8*)&ylds[((r0    )*128 + t)*24 + ci0];
            const short8 a1 = *(const short8*)&ylds[((r0 + 2)*128 + t)*24 + ci0];
            const short8 a2 = *(const short8*)&ylds[((rl2   )*128 + t)*24 + ci0];
            f32x4 acc = cb;
            acc = __builtin_amdgcn_mfma_f32_16x16x32_bf16(a0, Bl0, acc, 0, 0, 0);
            acc = __builtin_amdgcn_mfma_f32_16x16x32_bf16(a1, Bl1, acc, 0, 0, 0);
            acc = __builtin_amdgcn_mfma_f32_16x16x32_bf16(a2, Bl2, acc, 0, 0, 0);
            acc = __builtin_amdgcn_mfma_f32_16x16x32_bf16(a0, Bh0, acc, 0, 0, 0);
            acc = __builtin_amdgcn_mfma_f32_16x16x32_bf16(a1, Bh1, acc, 0, 0, 0);
            acc = __builtin_amdgcn_mfma_f32_16x16x32_bf16(a2, Bh2, acc, 0, 0, 0);
            #pragma unroll
            for (int r = 0; r < 4; r++) {
                const int tt = tg + ti*16 + quad*4 + r;
                if (tt < NT) {
                    float v = acc[r];
                    v = (v >= 0.f) ? v : al2*v;
                    xo[(size_t)tt*CH] = f2bf(v);
                }
            }
        }
    }
}

// -------------------------------------------------------------------------
// GRU via MFMA — R5 structure (proven 354 us) + R8: log2e folded into the
// MFMA weights.  r/z-gate weights & biases scaled by log2e, n-gate by
// 2*log2e -> sigmoid becomes v_exp(-acc) (neg modifier free) + add + rcp;
// kills one v_mul per sigmoid and the 2*aa muls (~48 cyc/step, issue-bound
// wave per R6).  prob path (acc8) unscaled, keeps sig_.
// -------------------------------------------------------------------------
__global__ __launch_bounds__(64) void gru_kernel(
    const unsigned short* __restrict__ xin,  // (NSEQ, NT, 16) bf16
    const float* __restrict__ h0,    // (NSEQ, 32)
    const float* __restrict__ w_ih,  // (96, 16)
    const float* __restrict__ w_hh,  // (96, 32)
    const float* __restrict__ b_ih, const float* __restrict__ b_hh,
    const float* __restrict__ fc_w, const float* __restrict__ fc_b,
    float* __restrict__ prob,        // (NSEQ, NT)
    float* __restrict__ hout)        // (NSEQ, 32)
{
    __shared__ unsigned short sv[16*72];     // [seq][x16|h32|pad16] bf16
    const int lane = threadIdx.x & 63;
    const int c    = lane & 15;
    const int quad = lane >> 4;
    const int base = blockIdx.x * 16;        // 481 blocks x 16 seq
    const float L2E = 1.4426950408889634f;

    // scale: r/z rows (g<64) by log2e; n rows (g>=64) by 2*log2e
    #define MKB(DST, G, CK)                                                    \
        { _Pragma("unroll") for (int j = 0; j < 8; j++) {                      \
            const int k = (CK)*32 + quad*8 + j;                                \
            const int g = (G);                                                 \
            const float sc_ = (g < 64) ? L2E : 2.f*L2E;                        \
            float wv_;                                                         \
            if (g < 64)      wv_ = (k < 16) ? w_ih[g*16 + k]                   \
                                  : (k < 48) ? w_hh[g*32 + k - 16] : 0.f;      \
            else if (g < 96) wv_ = (k < 16) ? w_ih[g*16 + k] : 0.f;            \
            else             wv_ = (k >= 16 && k < 48)                         \
                                  ? w_hh[(g-32)*32 + k - 16] : 0.f;            \
            DST[j] = (short)f2bf(wv_ * sc_); } }

    short8 B0a, B0b, B1a, B1b, B2a, B2b, B3a, B3b, B4a, B5a, B6a, B6b, B7a, B7b;
    MKB(B0a,       c, 0); MKB(B0b,       c, 1);   // r  units 0..15
    MKB(B1a,  16 + c, 0); MKB(B1b,  16 + c, 1);   // r  units 16..31
    MKB(B2a,  32 + c, 0); MKB(B2b,  32 + c, 1);   // z
    MKB(B3a,  48 + c, 0); MKB(B3b,  48 + c, 1);
    MKB(B4a,  64 + c, 0);                          // xn (chunk1 all-zero)
    MKB(B5a,  80 + c, 0);
    MKB(B6a,  96 + c, 0); MKB(B6b,  96 + c, 1);   // hn
    MKB(B7a, 112 + c, 0); MKB(B7b, 112 + c, 1);

    // FC fragment: same value in every col; k=16..47 <-> h units 0..31 (unscaled)
    short8 Bfa, Bfb;
    { _Pragma("unroll") for (int j = 0; j < 8; j++) {
        const int k0 = quad*8 + j;
        Bfa[j] = (short)((k0 >= 16) ? f2bf(fc_w[k0 - 16]) : 0);
        const int k1 = 32 + quad*8 + j;
        Bfb[j] = (short)((k1 < 48) ? f2bf(fc_w[k1 - 16]) : 0);
    } }

    const float bi0 = (b_ih[c]      + b_hh[c])      * L2E;
    const float bi1 = (b_ih[16 + c] + b_hh[16 + c]) * L2E;
    const float bi2 = (b_ih[32 + c] + b_hh[32 + c]) * L2E;
    const float bi3 = (b_ih[48 + c] + b_hh[48 + c]) * L2E;
    const float bi4 = b_ih[64 + c] * 2.f*L2E;
    const float bi5 = b_ih[80 + c] * 2.f*L2E;
    const float bi6 = b_hh[64 + c] * 2.f*L2E;
    const float bi7 = b_hh[80 + c] * 2.f*L2E;
    const float fb = fc_b[0];

    const f32x4 cb0 = {bi0, bi0, bi0, bi0};
    const f32x4 cb1 = {bi1, bi1, bi1, bi1};
    const f32x4 cb2 = {bi2, bi2, bi2, bi2};
    const f32x4 cb3 = {bi3, bi3, bi3, bi3};
    const f32x4 cb4 = {bi4, bi4, bi4, bi4};
    const f32x4 cb5 = {bi5, bi5, bi5, bi5};
    const f32x4 cb6 = {bi6, bi6, bi6, bi6};
    const f32x4 cb7 = {bi7, bi7, bi7, bi7};
    const f32x4 cb8 = {fb, fb, fb, fb};

    float hp00 = h0[(size_t)(base + quad*4 + 0)*HID + c];
    float hp01 = h0[(size_t)(base + quad*4 + 0)*HID + 16 + c];
    float hp10 = h0[(size_t)(base + quad*4 + 1)*HID + c];
    float hp11 = h0[(size_t)(base + quad*4 + 1)*HID + 16 + c];
    float hp20 = h0[(size_t)(base + quad*4 + 2)*HID + c];
    float hp21 = h0[(size_t)(base + quad*4 + 2)*HID + 16 + c];
    float hp30 = h0[(size_t)(base + quad*4 + 3)*HID + c];
    float hp31 = h0[(size_t)(base + quad*4 + 3)*HID + 16 + c];

    // ---- init LDS v-buffer ----
    *(uint2*)&sv[(lane >> 2)*72 + 48 + (lane & 3)*4] = make_uint2(0u, 0u);
    sv[(quad*4 + 0)*72 + 16 + c] = f2bf(hp00);  sv[(quad*4 + 0)*72 + 32 + c] = f2bf(hp01);
    sv[(quad*4 + 1)*72 + 16 + c] = f2bf(hp10);  sv[(quad*4 + 1)*72 + 32 + c] = f2bf(hp11);
    sv[(quad*4 + 2)*72 + 16 + c] = f2bf(hp20);  sv[(quad*4 + 2)*72 + 32 + c] = f2bf(hp21);
    sv[(quad*4 + 3)*72 + 16 + c] = f2bf(hp30);  sv[(quad*4 + 3)*72 + 32 + c] = f2bf(hp31);
    const unsigned short* xrow = xin + ((size_t)(base + (lane >> 2)))*NT*CH + (lane & 3)*4;
    {
        const uint2 x0v = *(const uint2*)(xrow);
        *(uint2*)&sv[(lane >> 2)*72 + (lane & 3)*4] = x0v;
    }
    uint2 nxA = *(const uint2*)(xrow + 1*CH);   // x(t=1)
    uint2 nxB = *(const uint2*)(xrow + 2*CH);   // x(t=2)
    __builtin_amdgcn_wave_barrier();

    #define GSTEP(R, HP0, HP1)                                                 \
        {                                                                      \
            const float rr0 = sige_(acc0[R]);                                  \
            const float rr1 = sige_(acc1[R]);                                  \
            const float zz0 = sige_(acc2[R]);                                  \
            const float zz1 = sige_(acc3[R]);                                  \
            const float aa0 = fmaf(rr0, acc6[R], acc4[R]);                     \
            const float aa1 = fmaf(rr1, acc7[R], acc5[R]);                     \
            const float nn0 = fmaf(2.f, sige_(aa0), -1.f);                     \
            const float nn1 = fmaf(2.f, sige_(aa1), -1.f);                     \
            HP0 = fmaf(zz0, HP0 - nn0, nn0);                                   \
            HP1 = fmaf(zz1, HP1 - nn1, nn1);                                   \
            unsigned hpk_;                                                     \
            asm("v_cvt_pk_bf16_f32 %0, %1, %2"                                 \
                : "=v"(hpk_) : "v"(HP0), "v"(HP1));                            \
            sv[(quad*4 + (R))*72 + 16 + c] = (unsigned short)hpk_;             \
            sv[(quad*4 + (R))*72 + 32 + c] = (unsigned short)(hpk_ >> 16);     \
        }

    for (int t = 0; t < NT; t++) {
        const short8 a0  = *(const short8*)&sv[c*72 + quad*8];        // k 0..31
        const short8 a1  = *(const short8*)&sv[c*72 + 32 + quad*8];   // k 32..63
        __builtin_amdgcn_wave_barrier();   // pin reads before this iter's writes

        // prefetch x(t+3)
        const int tn = (t + 3 < NT) ? t + 3 : NT - 1;
        const uint2 fx = *(const uint2*)(xrow + (size_t)tn*CH);

        f32x4 acc0 = __builtin_amdgcn_mfma_f32_16x16x32_bf16(a0, B0a, cb0, 0, 0, 0);
        f32x4 acc1 = __builtin_amdgcn_mfma_f32_16x16x32_bf16(a0, B1a, cb1, 0, 0, 0);
        f32x4 acc2 = __builtin_amdgcn_mfma_f32_16x16x32_bf16(a0, B2a, cb2, 0, 0, 0);
        f32x4 acc3 = __builtin_amdgcn_mfma_f32_16x16x32_bf16(a0, B3a, cb3, 0, 0, 0);
        f32x4 acc4 = __builtin_amdgcn_mfma_f32_16x16x32_bf16(a0, B4a, cb4, 0, 0, 0);
        f32x4 acc5 = __builtin_amdgcn_mfma_f32_16x16x32_bf16(a0, B5a, cb5, 0, 0, 0);
        f32x4 acc6 = __builtin_amdgcn_mfma_f32_16x16x32_bf16(a0, B6a, cb6, 0, 0, 0);
        f32x4 acc7 = __builtin_amdgcn_mfma_f32_16x16x32_bf16(a0, B7a, cb7, 0, 0, 0);
        f32x4 acc8 = __builtin_amdgcn_mfma_f32_16x16x32_bf16(a0, Bfa, cb8, 0, 0, 0);
        acc0 = __builtin_amdgcn_mfma_f32_16x16x32_bf16(a1, B0b, acc0, 0, 0, 0);
        acc1 = __builtin_amdgcn_mfma_f32_16x16x32_bf16(a1, B1b, acc1, 0, 0, 0);
        acc2 = __builtin_amdgcn_mfma_f32_16x16x32_bf16(a1, B2b, acc2, 0, 0, 0);
        acc3 = __builtin_amdgcn_mfma_f32_16x16x32_bf16(a1, B3b, acc3, 0, 0, 0);
        acc6 = __builtin_amdgcn_mfma_f32_16x16x32_bf16(a1, B6b, acc6, 0, 0, 0);
        acc7 = __builtin_amdgcn_mfma_f32_16x16x32_bf16(a1, B7b, acc7, 0, 0, 0);
        acc8 = __builtin_amdgcn_mfma_f32_16x16x32_bf16(a1, Bfb, acc8, 0, 0, 0);

        // prob[t-1]: acc8[R] = logit for seq quad*4+R (same in every col)
        if (t > 0 && c == 0) {
            prob[(size_t)(base + quad*4 + 0)*NT + (t - 1)] = sig_(acc8[0]);
            prob[(size_t)(base + quad*4 + 1)*NT + (t - 1)] = sig_(acc8[1]);
            prob[(size_t)(base + quad*4 + 2)*NT + (t - 1)] = sig_(acc8[2]);
            prob[(size_t)(base + quad*4 + 3)*NT + (t - 1)] = sig_(acc8[3]);
        }

        GSTEP(0, hp00, hp01);
        GSTEP(1, hp10, hp11);
        GSTEP(2, hp20, hp21);
        GSTEP(3, hp30, hp31);

        // stage x(t+1), rotate prefetch pipeline
        *(uint2*)&sv[(lane >> 2)*72 + (lane & 3)*4] = nxA;
        nxA = nxB; nxB = fx;
        __builtin_amdgcn_wave_barrier();
    }

    // prob for the final step (h_NT is in sv)
    {
        const short8 a0  = *(const short8*)&sv[c*72 + quad*8];
        const short8 a1  = *(const short8*)&sv[c*72 + 32 + quad*8];
        f32x4 acc8 = __builtin_amdgcn_mfma_f32_16x16x32_bf16(a0, Bfa, cb8, 0, 0, 0);
        acc8 = __builtin_amdgcn_mfma_f32_16x16x32_bf16(a1, Bfb, acc8, 0, 0, 0);
        if (c == 0) {
            prob[(size_t)(base + quad*4 + 0)*NT + (NT - 1)] = sig_(acc8[0]);
            prob[(size_t)(base + quad*4 + 1)*NT + (NT - 1)] = sig_(acc8[1]);
            prob[(size_t)(base + quad*4 + 2)*NT + (NT - 1)] = sig_(acc8[2]);
            prob[(size_t)(base + quad*4 + 3)*NT + (NT - 1)] = sig_(acc8[3]);
        }
    }

    hout[(size_t)(base + quad*4 + 0)*HID + c]      = hp00;
    hout[(size_t)(base + quad*4 + 0)*HID + 16 + c] = hp01;
    hout[(size_t)(base + quad*4 + 1)*HID + c]      = hp10;
    hout[(size_t)(base + quad*4 + 1)*HID + 16 + c] = hp11;
    hout[(size_t)(base + quad*4 + 2)*HID + c]      = hp20;
    hout[(size_t)(base + quad*4 + 2)*HID + 16 + c] = hp21;
    hout[(size_t)(base + quad*4 + 3)*HID + c]      = hp30;
    hout[(size_t)(base + quad*4 + 3)*HID + 16 + c] = hp31;
}

// -------------------------------------------------------------------------
extern "C" void kernel_launch(void* const* d_in, const int* in_sizes, int n_in,
                              void* d_out, int out_size, void* d_ws, size_t ws_size,
                              hipStream_t stream)
{
    const float* feat = (const float*)d_in[0];
    const float* h0   = (const float*)d_in[1];
    const float* w1   = (const float*)d_in[2];
    const float* b1   = (const float*)d_in[3];
    const float* a1   = (const float*)d_in[4];
    const float* w2   = (const float*)d_in[5];
    const float* b2   = (const float*)d_in[6];
    const float* a2   = (const float*)d_in[7];
    const float* wih  = (const float*)d_in[8];
    const float* whh  = (const float*)d_in[9];
    const float* bih  = (const float*)d_in[10];
    const float* bhh  = (const float*)d_in[11];
    const float* fcw  = (const float*)d_in[12];
    const float* fcb  = (const float*)d_in[13];

    unsigned short* xbuf = (unsigned short*)d_ws;            // 123.1 MB bf16
    unsigned short* y1   = xbuf + (size_t)NSEQ*NT*CH;        // 123.1 MB bf16 (b,f,t,ch)
    float* prob = (float*)d_out;                             // (B, F, T)
    float* hout = prob + (size_t)NSEQ*NT;                    // (1, NSEQ, 32)

    dim3 c1grid(NB, 241, 2);                                 // 2 f x 2 ch-halves x 256 t
    conv1_kernel<<<c1grid, 256, 0, stream>>>(feat, w1, b1, a1, y1);
    dim3 c2grid(NB, 121, 4);                                 // 4 f x 128 t per block
    conv2_kernel<<<c2grid, 256, 0, stream>>>(y1, w2, b2, a2, xbuf);
    gru_kernel<<<NSEQ/16, 64, 0, stream>>>(xbuf, h0, wih, whh, bih, bhh, fcw, fcb, prob, hout);
}

// Round 9
// 638.008 us; speedup vs baseline: 1.4880x; 1.0814x over previous
//
#include <hip/hip_runtime.h>

#define NF 481
#define NT 500
#define CH 16
#define HID 32
#define NB 16
#define NSEQ (NB*NF)   // 7696

typedef __attribute__((ext_vector_type(8))) short short8;
typedef __attribute__((ext_vector_type(4))) float f32x4;

// fast sigmoid — v_rcp instead of correctly-rounded divide (R10 win)
__device__ __forceinline__ float sig_(float v) {
    return __builtin_amdgcn_rcpf(1.0f + __expf(-v));
}
// sigmoid for PRE-SCALED logits: v = log2e * x  ->  1/(1+2^-v).
__device__ __forceinline__ float sige_(float v) {
    float e;
    asm("v_exp_f32 %0, -%1" : "=v"(e) : "v"(v));
    return __builtin_amdgcn_rcpf(1.0f + e);
}

__device__ __forceinline__ unsigned short f2bf(float f) {
    unsigned u = __float_as_uint(f);
    u = (u + 0x7fffu + ((u >> 16) & 1u)) >> 16;   // RNE
    return (unsigned short)u;
}
__device__ __forceinline__ unsigned int pk2(float a, float b) {
    return (unsigned int)f2bf(a) | ((unsigned int)f2bf(b) << 16);
}
__device__ __forceinline__ float bf2f(short s) {
    return __uint_as_float(((unsigned)(unsigned short)s) << 16);
}
__device__ __forceinline__ float4 prelu4(float4 v, float a) {
    v.x = (v.x >= 0.f) ? v.x : a*v.x;
    v.y = (v.y >= 0.f) ? v.y : a*v.y;
    v.z = (v.z >= 0.f) ? v.z : a*v.z;
    v.w = (v.w >= 0.f) ? v.w : a*v.w;
    return v;
}

#define FMA4(Q, W, V)                     \
    Q.x = fmaf((W), (V).x, Q.x);          \
    Q.y = fmaf((W), (V).y, Q.y);          \
    Q.z = fmaf((W), (V).z, Q.z);          \
    Q.w = fmaf((W), (V).w, Q.w)

// -------------------------------------------------------------------------
// Pass 1: conv1(4->16,k9,p4) + PReLU -> y1 (b,f,t,ch) bf16.  R5 version
// verbatim — the proven local optimum (R3 dup / R7 LDS / R8 ch-split all
// regressed: any extra memory-issue per FMA loses).
// -------------------------------------------------------------------------
#define P1TAP(D, K1)                                                           \
    {                                                                          \
        const int gf = f + (K1) - 4;                                           \
        if (gf >= 0 && gf < NF) {                                              \
            const float4 v = *(const float4*)(feat +                           \
                ((size_t)(b*4 + (D))*NF + gf)*NT + tc0);                       \
            FMA4(q0,  w1[ 0*36 + (D)*9 + (K1)], v);                            \
            FMA4(q1,  w1[ 1*36 + (D)*9 + (K1)], v);                            \
            FMA4(q2,  w1[ 2*36 + (D)*9 + (K1)], v);                            \
            FMA4(q3,  w1[ 3*36 + (D)*9 + (K1)], v);                            \
            FMA4(q4,  w1[ 4*36 + (D)*9 + (K1)], v);                            \
            FMA4(q5,  w1[ 5*36 + (D)*9 + (K1)], v);                            \
            FMA4(q6,  w1[ 6*36 + (D)*9 + (K1)], v);                            \
            FMA4(q7,  w1[ 7*36 + (D)*9 + (K1)], v);                            \
            FMA4(q8,  w1[ 8*36 + (D)*9 + (K1)], v);                            \
            FMA4(q9,  w1[ 9*36 + (D)*9 + (K1)], v);                            \
            FMA4(q10, w1[10*36 + (D)*9 + (K1)], v);                            \
            FMA4(q11, w1[11*36 + (D)*9 + (K1)], v);                            \
            FMA4(q12, w1[12*36 + (D)*9 + (K1)], v);                            \
            FMA4(q13, w1[13*36 + (D)*9 + (K1)], v);                            \
            FMA4(q14, w1[14*36 + (D)*9 + (K1)], v);                            \
            FMA4(q15, w1[15*36 + (D)*9 + (K1)], v);                            \
        }                                                                      \
    }

#define STX(OP, E, COMP)                                                       \
    *(uint4*)((OP) + (E)*CH) = make_uint4(                                     \
        pk2(q0.COMP, q1.COMP),  pk2(q2.COMP, q3.COMP),                         \
        pk2(q4.COMP, q5.COMP),  pk2(q6.COMP, q7.COMP));                        \
    *(uint4*)((OP) + (E)*CH + 8) = make_uint4(                                 \
        pk2(q8.COMP, q9.COMP),  pk2(q10.COMP, q11.COMP),                       \
        pk2(q12.COMP, q13.COMP), pk2(q14.COMP, q15.COMP))

__global__ __launch_bounds__(256) void conv1_kernel(
    const float* __restrict__ feat,
    const float* __restrict__ w1, const float* __restrict__ b1, const float* __restrict__ a1p,
    unsigned short* __restrict__ y1)          // (b, f, t, ch) bf16
{
    const int b    = blockIdx.x;
    const int wv   = threadIdx.x >> 6;
    const int lane = threadIdx.x & 63;
    const int f    = blockIdx.y*4 + wv;
    if (f >= NF) return;
    const int gt0  = blockIdx.z*256 + lane*4;
    const int tc0  = (gt0 <= NT-4) ? gt0 : (NT-4);
    const float al1 = a1p[0];

    float4 q0  = make_float4(b1[0],b1[0],b1[0],b1[0]);
    float4 q1  = make_float4(b1[1],b1[1],b1[1],b1[1]);
    float4 q2  = make_float4(b1[2],b1[2],b1[2],b1[2]);
    float4 q3  = make_float4(b1[3],b1[3],b1[3],b1[3]);
    float4 q4  = make_float4(b1[4],b1[4],b1[4],b1[4]);
    float4 q5  = make_float4(b1[5],b1[5],b1[5],b1[5]);
    float4 q6  = make_float4(b1[6],b1[6],b1[6],b1[6]);
    float4 q7  = make_float4(b1[7],b1[7],b1[7],b1[7]);
    float4 q8  = make_float4(b1[8],b1[8],b1[8],b1[8]);
    float4 q9  = make_float4(b1[9],b1[9],b1[9],b1[9]);
    float4 q10 = make_float4(b1[10],b1[10],b1[10],b1[10]);
    float4 q11 = make_float4(b1[11],b1[11],b1[11],b1[11]);
    float4 q12 = make_float4(b1[12],b1[12],b1[12],b1[12]);
    float4 q13 = make_float4(b1[13],b1[13],b1[13],b1[13]);
    float4 q14 = make_float4(b1[14],b1[14],b1[14],b1[14]);
    float4 q15 = make_float4(b1[15],b1[15],b1[15],b1[15]);

    #pragma unroll
    for (int d = 0; d < 4; d++) {
        P1TAP(d, 0); P1TAP(d, 1); P1TAP(d, 2); P1TAP(d, 3); P1TAP(d, 4);
        P1TAP(d, 5); P1TAP(d, 6); P1TAP(d, 7); P1TAP(d, 8);
    }

    if (gt0 < NT) {
        q0  = prelu4(q0,  al1); q1  = prelu4(q1,  al1);
        q2  = prelu4(q2,  al1); q3  = prelu4(q3,  al1);
        q4  = prelu4(q4,  al1); q5  = prelu4(q5,  al1);
        q6  = prelu4(q6,  al1); q7  = prelu4(q7,  al1);
        q8  = prelu4(q8,  al1); q9  = prelu4(q9,  al1);
        q10 = prelu4(q10, al1); q11 = prelu4(q11, al1);
        q12 = prelu4(q12, al1); q13 = prelu4(q13, al1);
        q14 = prelu4(q14, al1); q15 = prelu4(q15, al1);
        unsigned short* op = y1 + ((size_t)(b*NF + f)*NT + gt0)*CH;
        STX(op, 0, x); STX(op, 1, y); STX(op, 2, z); STX(op, 3, w);
    }
}

// -------------------------------------------------------------------------
// Pass 2: conv2(16->16,k5,p2) via MFMA + PReLU -> x (n,t,16).
// R9: operand swap — mfma(W, data, C) gives D[row=cout][col=t] (fragment
// layouts are symmetric, same register bits serve either slot).  Each lane
// then holds 4 CONSECUTIVE channels at one t -> 2 pk2 + ONE uint2 store per
// tile (was 4 scalar 2B stores + 4 bounds checks).  Bias now per-row.
// -------------------------------------------------------------------------
__global__ __launch_bounds__(256) void conv2_kernel(
    const unsigned short* __restrict__ y1,    // (b, f, t, ch) bf16
    const float* __restrict__ w2, const float* __restrict__ b2, const float* __restrict__ a2p,
    unsigned short* __restrict__ xout)
{
    __shared__ unsigned short ylds[8*128*24];    // 48 KB: [row8][t128][ch16+pad8]
    const int b    = blockIdx.x;
    const int f0   = blockIdx.y * 4;
    const int tg   = blockIdx.z * 128;
    const int tid  = threadIdx.x;
    const int wid  = tid >> 6;
    const int lane = tid & 63;

    #pragma unroll
    for (int i = 0; i < 8; i++) {
        const int idx  = tid + i*256;        // 0..2047
        const int row  = idx >> 8;           // 0..7
        const int tt   = (idx >> 1) & 127;
        const int half = idx & 1;
        const int fr   = f0 - 2 + row;
        const int gt   = tg + tt;
        uint4 v = make_uint4(0u, 0u, 0u, 0u);
        if (fr >= 0 && fr < NF && gt < NT)
            v = *(const uint4*)(y1 + ((size_t)(b*NF + fr)*NT + gt)*CH + half*8);
        *(uint4*)&ylds[(row*128 + tt)*24 + half*8] = v;
    }
    __syncthreads();

    const int c    = lane & 15;
    const int quad = lane >> 4;
    const int f    = f0 + wid;
    if (f < NF) {
        const float al2 = a2p[0];
        short8 Bh0, Bh1, Bh2, Bl0, Bl1, Bl2;
        #define MKB2(BH, BL, Q)                                                \
            { _Pragma("unroll") for (int j = 0; j < 8; j++) {                  \
                const int ci = (quad & 1)*8 + j;                               \
                const int kk = 2*(Q) + (quad >> 1);                            \
                float w = 0.f;                                                 \
                if (kk < 5) w = w2[c*80 + ci*5 + kk];                          \
                const unsigned short hb = f2bf(w);                             \
                const float hf = bf2f((short)hb);                              \
                BH[j] = (short)hb;                                             \
                BL[j] = (short)f2bf(w - hf); } }
        MKB2(Bh0, Bl0, 0); MKB2(Bh1, Bl1, 1); MKB2(Bh2, Bl2, 2);
        #undef MKB2

        // bias per ROW now: acc[r] is cout = quad*4 + r
        const f32x4 cb = {b2[quad*4 + 0], b2[quad*4 + 1],
                          b2[quad*4 + 2], b2[quad*4 + 3]};
        const int ci0 = (quad & 1)*8;
        const int r0  = wid + (quad >> 1);
        unsigned short* xo = xout + ((size_t)(b*NF + f)*NT)*CH + quad*4;

        #pragma unroll
        for (int ti = 0; ti < 8; ti++) {
            const int t = ti*16 + c;             // B col = t within the 128-slice
            const int rl2 = (r0 + 4 > 7) ? 7 : (r0 + 4);
            const short8 a0 = *(const short8*)&ylds[((r0    )*128 + t)*24 + ci0];
            const short8 a1 = *(const short8*)&ylds[((r0 + 2)*128 + t)*24 + ci0];
            const short8 a2 = *(const short8*)&ylds[((rl2   )*128 + t)*24 + ci0];
            f32x4 acc = cb;
            acc = __builtin_amdgcn_mfma_f32_16x16x32_bf16(Bl0, a0, acc, 0, 0, 0);
            acc = __builtin_amdgcn_mfma_f32_16x16x32_bf16(Bl1, a1, acc, 0, 0, 0);
            acc = __builtin_amdgcn_mfma_f32_16x16x32_bf16(Bl2, a2, acc, 0, 0, 0);
            acc = __builtin_amdgcn_mfma_f32_16x16x32_bf16(Bh0, a0, acc, 0, 0, 0);
            acc = __builtin_amdgcn_mfma_f32_16x16x32_bf16(Bh1, a1, acc, 0, 0, 0);
            acc = __builtin_amdgcn_mfma_f32_16x16x32_bf16(Bh2, a2, acc, 0, 0, 0);
            // D layout: row = quad*4+r = cout, col = c = t
            const int tt = tg + t;
            if (tt < NT) {
                float v0 = acc[0], v1 = acc[1], v2 = acc[2], v3 = acc[3];
                v0 = (v0 >= 0.f) ? v0 : al2*v0;
                v1 = (v1 >= 0.f) ? v1 : al2*v1;
                v2 = (v2 >= 0.f) ? v2 : al2*v2;
                v3 = (v3 >= 0.f) ? v3 : al2*v3;
                *(uint2*)(xo + (size_t)tt*CH) = make_uint2(pk2(v0, v1), pk2(v2, v3));
            }
        }
    }
}

// -------------------------------------------------------------------------
// GRU via MFMA — R8 log2e version verbatim (proven 342 us).
// -------------------------------------------------------------------------
__global__ __launch_bounds__(64) void gru_kernel(
    const unsigned short* __restrict__ xin,  // (NSEQ, NT, 16) bf16
    const float* __restrict__ h0,    // (NSEQ, 32)
    const float* __restrict__ w_ih,  // (96, 16)
    const float* __restrict__ w_hh,  // (96, 32)
    const float* __restrict__ b_ih, const float* __restrict__ b_hh,
    const float* __restrict__ fc_w, const float* __restrict__ fc_b,
    float* __restrict__ prob,        // (NSEQ, NT)
    float* __restrict__ hout)        // (NSEQ, 32)
{
    __shared__ unsigned short sv[16*72];     // [seq][x16|h32|pad16] bf16
    const int lane = threadIdx.x & 63;
    const int c    = lane & 15;
    const int quad = lane >> 4;
    const int base = blockIdx.x * 16;        // 481 blocks x 16 seq
    const float L2E = 1.4426950408889634f;

    #define MKB(DST, G, CK)                                                    \
        { _Pragma("unroll") for (int j = 0; j < 8; j++) {                      \
            const int k = (CK)*32 + quad*8 + j;                                \
            const int g = (G);                                                 \
            const float sc_ = (g < 64) ? L2E : 2.f*L2E;                        \
            float wv_;                                                         \
            if (g < 64)      wv_ = (k < 16) ? w_ih[g*16 + k]                   \
                                  : (k < 48) ? w_hh[g*32 + k - 16] : 0.f;      \
            else if (g < 96) wv_ = (k < 16) ? w_ih[g*16 + k] : 0.f;            \
            else             wv_ = (k >= 16 && k < 48)                         \
                                  ? w_hh[(g-32)*32 + k - 16] : 0.f;            \
            DST[j] = (short)f2bf(wv_ * sc_); } }

    short8 B0a, B0b, B1a, B1b, B2a, B2b, B3a, B3b, B4a, B5a, B6a, B6b, B7a, B7b;
    MKB(B0a,       c, 0); MKB(B0b,       c, 1);   // r  units 0..15
    MKB(B1a,  16 + c, 0); MKB(B1b,  16 + c, 1);   // r  units 16..31
    MKB(B2a,  32 + c, 0); MKB(B2b,  32 + c, 1);   // z
    MKB(B3a,  48 + c, 0); MKB(B3b,  48 + c, 1);
    MKB(B4a,  64 + c, 0);                          // xn (chunk1 all-zero)
    MKB(B5a,  80 + c, 0);
    MKB(B6a,  96 + c, 0); MKB(B6b,  96 + c, 1);   // hn
    MKB(B7a, 112 + c, 0); MKB(B7b, 112 + c, 1);

    // FC fragment: same value in every col; k=16..47 <-> h units 0..31 (unscaled)
    short8 Bfa, Bfb;
    { _Pragma("unroll") for (int j = 0; j < 8; j++) {
        const int k0 = quad*8 + j;
        Bfa[j] = (short)((k0 >= 16) ? f2bf(fc_w[k0 - 16]) : 0);
        const int k1 = 32 + quad*8 + j;
        Bfb[j] = (short)((k1 < 48) ? f2bf(fc_w[k1 - 16]) : 0);
    } }

    const float bi0 = (b_ih[c]      + b_hh[c])      * L2E;
    const float bi1 = (b_ih[16 + c] + b_hh[16 + c]) * L2E;
    const float bi2 = (b_ih[32 + c] + b_hh[32 + c]) * L2E;
    const float bi3 = (b_ih[48 + c] + b_hh[48 + c]) * L2E;
    const float bi4 = b_ih[64 + c] * 2.f*L2E;
    const float bi5 = b_ih[80 + c] * 2.f*L2E;
    const float bi6 = b_hh[64 + c] * 2.f*L2E;
    const float bi7 = b_hh[80 + c] * 2.f*L2E;
    const float fb = fc_b[0];

    const f32x4 cb0 = {bi0, bi0, bi0, bi0};
    const f32x4 cb1 = {bi1, bi1, bi1, bi1};
    const f32x4 cb2 = {bi2, bi2, bi2, bi2};
    const f32x4 cb3 = {bi3, bi3, bi3, bi3};
    const f32x4 cb4 = {bi4, bi4, bi4, bi4};
    const f32x4 cb5 = {bi5, bi5, bi5, bi5};
    const f32x4 cb6 = {bi6, bi6, bi6, bi6};
    const f32x4 cb7 = {bi7, bi7, bi7, bi7};
    const f32x4 cb8 = {fb, fb, fb, fb};

    float hp00 = h0[(size_t)(base + quad*4 + 0)*HID + c];
    float hp01 = h0[(size_t)(base + quad*4 + 0)*HID + 16 + c];
    float hp10 = h0[(size_t)(base + quad*4 + 1)*HID + c];
    float hp11 = h0[(size_t)(base + quad*4 + 1)*HID + 16 + c];
    float hp20 = h0[(size_t)(base + quad*4 + 2)*HID + c];
    float hp21 = h0[(size_t)(base + quad*4 + 2)*HID + 16 + c];
    float hp30 = h0[(size_t)(base + quad*4 + 3)*HID + c];
    float hp31 = h0[(size_t)(base + quad*4 + 3)*HID + 16 + c];

    // ---- init LDS v-buffer ----
    *(uint2*)&sv[(lane >> 2)*72 + 48 + (lane & 3)*4] = make_uint2(0u, 0u);
    sv[(quad*4 + 0)*72 + 16 + c] = f2bf(hp00);  sv[(quad*4 + 0)*72 + 32 + c] = f2bf(hp01);
    sv[(quad*4 + 1)*72 + 16 + c] = f2bf(hp10);  sv[(quad*4 + 1)*72 + 32 + c] = f2bf(hp11);
    sv[(quad*4 + 2)*72 + 16 + c] = f2bf(hp20);  sv[(quad*4 + 2)*72 + 32 + c] = f2bf(hp21);
    sv[(quad*4 + 3)*72 + 16 + c] = f2bf(hp30);  sv[(quad*4 + 3)*72 + 32 + c] = f2bf(hp31);
    const unsigned short* xrow = xin + ((size_t)(base + (lane >> 2)))*NT*CH + (lane & 3)*4;
    {
        const uint2 x0v = *(const uint2*)(xrow);
        *(uint2*)&sv[(lane >> 2)*72 + (lane & 3)*4] = x0v;
    }
    uint2 nxA = *(const uint2*)(xrow + 1*CH);   // x(t=1)
    uint2 nxB = *(const uint2*)(xrow + 2*CH);   // x(t=2)
    __builtin_amdgcn_wave_barrier();

    #define GSTEP(R, HP0, HP1)                                                 \
        {                                                                      \
            const float rr0 = sige_(acc0[R]);                                  \
            const float rr1 = sige_(acc1[R]);                                  \
            const float zz0 = sige_(acc2[R]);                                  \
            const float zz1 = sige_(acc3[R]);                                  \
            const float aa0 = fmaf(rr0, acc6[R], acc4[R]);                     \
            const float aa1 = fmaf(rr1, acc7[R], acc5[R]);                     \
            const float nn0 = fmaf(2.f, sige_(aa0), -1.f);                     \
            const float nn1 = fmaf(2.f, sige_(aa1), -1.f);                     \
            HP0 = fmaf(zz0, HP0 - nn0, nn0);                                   \
            HP1 = fmaf(zz1, HP1 - nn1, nn1);                                   \
            unsigned hpk_;                                                     \
            asm("v_cvt_pk_bf16_f32 %0, %1, %2"                                 \
                : "=v"(hpk_) : "v"(HP0), "v"(HP1));                            \
            sv[(quad*4 + (R))*72 + 16 + c] = (unsigned short)hpk_;             \
            sv[(quad*4 + (R))*72 + 32 + c] = (unsigned short)(hpk_ >> 16);     \
        }

    for (int t = 0; t < NT; t++) {
        const short8 a0  = *(const short8*)&sv[c*72 + quad*8];        // k 0..31
        const short8 a1  = *(const short8*)&sv[c*72 + 32 + quad*8];   // k 32..63
        __builtin_amdgcn_wave_barrier();   // pin reads before this iter's writes

        // prefetch x(t+3)
        const int tn = (t + 3 < NT) ? t + 3 : NT - 1;
        const uint2 fx = *(const uint2*)(xrow + (size_t)tn*CH);

        f32x4 acc0 = __builtin_amdgcn_mfma_f32_16x16x32_bf16(a0, B0a, cb0, 0, 0, 0);
        f32x4 acc1 = __builtin_amdgcn_mfma_f32_16x16x32_bf16(a0, B1a, cb1, 0, 0, 0);
        f32x4 acc2 = __builtin_amdgcn_mfma_f32_16x16x32_bf16(a0, B2a, cb2, 0, 0, 0);
        f32x4 acc3 = __builtin_amdgcn_mfma_f32_16x16x32_bf16(a0, B3a, cb3, 0, 0, 0);
        f32x4 acc4 = __builtin_amdgcn_mfma_f32_16x16x32_bf16(a0, B4a, cb4, 0, 0, 0);
        f32x4 acc5 = __builtin_amdgcn_mfma_f32_16x16x32_bf16(a0, B5a, cb5, 0, 0, 0);
        f32x4 acc6 = __builtin_amdgcn_mfma_f32_16x16x32_bf16(a0, B6a, cb6, 0, 0, 0);
        f32x4 acc7 = __builtin_amdgcn_mfma_f32_16x16x32_bf16(a0, B7a, cb7, 0, 0, 0);
        f32x4 acc8 = __builtin_amdgcn_mfma_f32_16x16x32_bf16(a0, Bfa, cb8, 0, 0, 0);
        acc0 = __builtin_amdgcn_mfma_f32_16x16x32_bf16(a1, B0b, acc0, 0, 0, 0);
        acc1 = __builtin_amdgcn_mfma_f32_16x16x32_bf16(a1, B1b, acc1, 0, 0, 0);
        acc2 = __builtin_amdgcn_mfma_f32_16x16x32_bf16(a1, B2b, acc2, 0, 0, 0);
        acc3 = __builtin_amdgcn_mfma_f32_16x16x32_bf16(a1, B3b, acc3, 0, 0, 0);
        acc6 = __builtin_amdgcn_mfma_f32_16x16x32_bf16(a1, B6b, acc6, 0, 0, 0);
        acc7 = __builtin_amdgcn_mfma_f32_16x16x32_bf16(a1, B7b, acc7, 0, 0, 0);
        acc8 = __builtin_amdgcn_mfma_f32_16x16x32_bf16(a1, Bfb, acc8, 0, 0, 0);

        // prob[t-1]: acc8[R] = logit for seq quad*4+R (same in every col)
        if (t > 0 && c == 0) {
            prob[(size_t)(base + quad*4 + 0)*NT + (t - 1)] = sig_(acc8[0]);
            prob[(size_t)(base + quad*4 + 1)*NT + (t - 1)] = sig_(acc8[1]);
            prob[(size_t)(base + quad*4 + 2)*NT + (t - 1)] = sig_(acc8[2]);
            prob[(size_t)(base + quad*4 + 3)*NT + (t - 1)] = sig_(acc8[3]);
        }

        GSTEP(0, hp00, hp01);
        GSTEP(1, hp10, hp11);
        GSTEP(2, hp20, hp21);
        GSTEP(3, hp30, hp31);

        // stage x(t+1), rotate prefetch pipeline
        *(uint2*)&sv[(lane >> 2)*72 + (lane & 3)*4] = nxA;
        nxA = nxB; nxB = fx;
        __builtin_amdgcn_wave_barrier();
    }

    // prob for the final step (h_NT is in sv)
    {
        const short8 a0  = *(const short8*)&sv[c*72 + quad*8];
        const short8 a1  = *(const short8*)&sv[c*72 + 32 + quad*8];
        f32x4 acc8 = __builtin_amdgcn_mfma_f32_16x16x32_bf16(a0, Bfa, cb8, 0, 0, 0);
        acc8 = __builtin_amdgcn_mfma_f32_16x16x32_bf16(a1, Bfb, acc8, 0, 0, 0);
        if (c == 0) {
            prob[(size_t)(base + quad*4 + 0)*NT + (NT - 1)] = sig_(acc8[0]);
            prob[(size_t)(base + quad*4 + 1)*NT + (NT - 1)] = sig_(acc8[1]);
            prob[(size_t)(base + quad*4 + 2)*NT + (NT - 1)] = sig_(acc8[2]);
            prob[(size_t)(base + quad*4 + 3)*NT + (NT - 1)] = sig_(acc8[3]);
        }
    }

    hout[(size_t)(base + quad*4 + 0)*HID + c]      = hp00;
    hout[(size_t)(base + quad*4 + 0)*HID + 16 + c] = hp01;
    hout[(size_t)(base + quad*4 + 1)*HID + c]      = hp10;
    hout[(size_t)(base + quad*4 + 1)*HID + 16 + c] = hp11;
    hout[(size_t)(base + quad*4 + 2)*HID + c]      = hp20;
    hout[(size_t)(base + quad*4 + 2)*HID + 16 + c] = hp21;
    hout[(size_t)(base + quad*4 + 3)*HID + c]      = hp30;
    hout[(size_t)(base + quad*4 + 3)*HID + 16 + c] = hp31;
}

// -------------------------------------------------------------------------
extern "C" void kernel_launch(void* const* d_in, const int* in_sizes, int n_in,
                              void* d_out, int out_size, void* d_ws, size_t ws_size,
                              hipStream_t stream)
{
    const float* feat = (const float*)d_in[0];
    const float* h0   = (const float*)d_in[1];
    const float* w1   = (const float*)d_in[2];
    const float* b1   = (const float*)d_in[3];
    const float* a1   = (const float*)d_in[4];
    const float* w2   = (const float*)d_in[5];
    const float* b2   = (const float*)d_in[6];
    const float* a2   = (const float*)d_in[7];
    const float* wih  = (const float*)d_in[8];
    const float* whh  = (const float*)d_in[9];
    const float* bih  = (const float*)d_in[10];
    const float* bhh  = (const float*)d_in[11];
    const float* fcw  = (const float*)d_in[12];
    const float* fcb  = (const float*)d_in[13];

    unsigned short* xbuf = (unsigned short*)d_ws;            // 123.1 MB bf16
    unsigned short* y1   = xbuf + (size_t)NSEQ*NT*CH;        // 123.1 MB bf16 (b,f,t,ch)
    float* prob = (float*)d_out;                             // (B, F, T)
    float* hout = prob + (size_t)NSEQ*NT;                    // (1, NSEQ, 32)

    dim3 c1grid(NB, 121, 2);                                 // 4 f-waves x 256 t
    conv1_kernel<<<c1grid, 256, 0, stream>>>(feat, w1, b1, a1, y1);
    dim3 c2grid(NB, 121, 4);                                 // 4 f x 128 t per block
    conv2_kernel<<<c2grid, 256, 0, stream>>>(y1, w2, b2, a2, xbuf);
    gru_kernel<<<NSEQ/16, 64, 0, stream>>>(xbuf, h0, wih, whh, bih, bhh, fcw, fcb, prob, hout);
}

// Round 10
// 582.686 us; speedup vs baseline: 1.6293x; 1.0949x over previous
//
#include <hip/hip_runtime.h>

#define NF 481
#define NT 500
#define CH 16
#define HID 32
#define NB 16
#define NSEQ (NB*NF)   // 7696

typedef __attribute__((ext_vector_type(8))) short short8;
typedef __attribute__((ext_vector_type(4))) float f32x4;

union S8U4 { short8 s; uint4 u; };

// fast sigmoid — v_rcp instead of correctly-rounded divide (R10 win)
__device__ __forceinline__ float sig_(float v) {
    return __builtin_amdgcn_rcpf(1.0f + __expf(-v));
}
// sigmoid for PRE-SCALED logits: v = log2e * x  ->  1/(1+2^-v).
__device__ __forceinline__ float sige_(float v) {
    float e;
    asm("v_exp_f32 %0, -%1" : "=v"(e) : "v"(v));
    return __builtin_amdgcn_rcpf(1.0f + e);
}

__device__ __forceinline__ unsigned short f2bf(float f) {
    unsigned u = __float_as_uint(f);
    u = (u + 0x7fffu + ((u >> 16) & 1u)) >> 16;   // RNE
    return (unsigned short)u;
}
__device__ __forceinline__ unsigned int pk2(float a, float b) {
    return (unsigned int)f2bf(a) | ((unsigned int)f2bf(b) << 16);
}
__device__ __forceinline__ float bf2f(short s) {
    return __uint_as_float(((unsigned)(unsigned short)s) << 16);
}
__device__ __forceinline__ float4 prelu4(float4 v, float a) {
    v.x = (v.x >= 0.f) ? v.x : a*v.x;
    v.y = (v.y >= 0.f) ? v.y : a*v.y;
    v.z = (v.z >= 0.f) ? v.z : a*v.z;
    v.w = (v.w >= 0.f) ? v.w : a*v.w;
    return v;
}

#define FMA4(Q, W, V)                     \
    Q.x = fmaf((W), (V).x, Q.x);          \
    Q.y = fmaf((W), (V).y, Q.y);          \
    Q.z = fmaf((W), (V).z, Q.z);          \
    Q.w = fmaf((W), (V).w, Q.w)

// -------------------------------------------------------------------------
// Pass 1: conv1(4->16,k9,p4) + PReLU -> y1 (b,f,t,ch) bf16.  (R9 verbatim)
// -------------------------------------------------------------------------
#define P1TAP(D, K1)                                                           \
    {                                                                          \
        const int gf = f + (K1) - 4;                                           \
        if (gf >= 0 && gf < NF) {                                              \
            const float4 v = *(const float4*)(feat +                           \
                ((size_t)(b*4 + (D))*NF + gf)*NT + tc0);                       \
            FMA4(q0,  w1[ 0*36 + (D)*9 + (K1)], v);                            \
            FMA4(q1,  w1[ 1*36 + (D)*9 + (K1)], v);                            \
            FMA4(q2,  w1[ 2*36 + (D)*9 + (K1)], v);                            \
            FMA4(q3,  w1[ 3*36 + (D)*9 + (K1)], v);                            \
            FMA4(q4,  w1[ 4*36 + (D)*9 + (K1)], v);                            \
            FMA4(q5,  w1[ 5*36 + (D)*9 + (K1)], v);                            \
            FMA4(q6,  w1[ 6*36 + (D)*9 + (K1)], v);                            \
            FMA4(q7,  w1[ 7*36 + (D)*9 + (K1)], v);                            \
            FMA4(q8,  w1[ 8*36 + (D)*9 + (K1)], v);                            \
            FMA4(q9,  w1[ 9*36 + (D)*9 + (K1)], v);                            \
            FMA4(q10, w1[10*36 + (D)*9 + (K1)], v);                            \
            FMA4(q11, w1[11*36 + (D)*9 + (K1)], v);                            \
            FMA4(q12, w1[12*36 + (D)*9 + (K1)], v);                            \
            FMA4(q13, w1[13*36 + (D)*9 + (K1)], v);                            \
            FMA4(q14, w1[14*36 + (D)*9 + (K1)], v);                            \
            FMA4(q15, w1[15*36 + (D)*9 + (K1)], v);                            \
        }                                                                      \
    }

#define STX(OP, E, COMP)                                                       \
    *(uint4*)((OP) + (E)*CH) = make_uint4(                                     \
        pk2(q0.COMP, q1.COMP),  pk2(q2.COMP, q3.COMP),                         \
        pk2(q4.COMP, q5.COMP),  pk2(q6.COMP, q7.COMP));                        \
    *(uint4*)((OP) + (E)*CH + 8) = make_uint4(                                 \
        pk2(q8.COMP, q9.COMP),  pk2(q10.COMP, q11.COMP),                       \
        pk2(q12.COMP, q13.COMP), pk2(q14.COMP, q15.COMP))

__global__ __launch_bounds__(256) void conv1_kernel(
    const float* __restrict__ feat,
    const float* __restrict__ w1, const float* __restrict__ b1, const float* __restrict__ a1p,
    unsigned short* __restrict__ y1)          // (b, f, t, ch) bf16
{
    const int b    = blockIdx.x;
    const int wv   = threadIdx.x >> 6;
    const int lane = threadIdx.x & 63;
    const int f    = blockIdx.y*4 + wv;
    if (f >= NF) return;
    const int gt0  = blockIdx.z*256 + lane*4;
    const int tc0  = (gt0 <= NT-4) ? gt0 : (NT-4);
    const float al1 = a1p[0];

    float4 q0  = make_float4(b1[0],b1[0],b1[0],b1[0]);
    float4 q1  = make_float4(b1[1],b1[1],b1[1],b1[1]);
    float4 q2  = make_float4(b1[2],b1[2],b1[2],b1[2]);
    float4 q3  = make_float4(b1[3],b1[3],b1[3],b1[3]);
    float4 q4  = make_float4(b1[4],b1[4],b1[4],b1[4]);
    float4 q5  = make_float4(b1[5],b1[5],b1[5],b1[5]);
    float4 q6  = make_float4(b1[6],b1[6],b1[6],b1[6]);
    float4 q7  = make_float4(b1[7],b1[7],b1[7],b1[7]);
    float4 q8  = make_float4(b1[8],b1[8],b1[8],b1[8]);
    float4 q9  = make_float4(b1[9],b1[9],b1[9],b1[9]);
    float4 q10 = make_float4(b1[10],b1[10],b1[10],b1[10]);
    float4 q11 = make_float4(b1[11],b1[11],b1[11],b1[11]);
    float4 q12 = make_float4(b1[12],b1[12],b1[12],b1[12]);
    float4 q13 = make_float4(b1[13],b1[13],b1[13],b1[13]);
    float4 q14 = make_float4(b1[14],b1[14],b1[14],b1[14]);
    float4 q15 = make_float4(b1[15],b1[15],b1[15],b1[15]);

    #pragma unroll
    for (int d = 0; d < 4; d++) {
        P1TAP(d, 0); P1TAP(d, 1); P1TAP(d, 2); P1TAP(d, 3); P1TAP(d, 4);
        P1TAP(d, 5); P1TAP(d, 6); P1TAP(d, 7); P1TAP(d, 8);
    }

    if (gt0 < NT) {
        q0  = prelu4(q0,  al1); q1  = prelu4(q1,  al1);
        q2  = prelu4(q2,  al1); q3  = prelu4(q3,  al1);
        q4  = prelu4(q4,  al1); q5  = prelu4(q5,  al1);
        q6  = prelu4(q6,  al1); q7  = prelu4(q7,  al1);
        q8  = prelu4(q8,  al1); q9  = prelu4(q9,  al1);
        q10 = prelu4(q10, al1); q11 = prelu4(q11, al1);
        q12 = prelu4(q12, al1); q13 = prelu4(q13, al1);
        q14 = prelu4(q14, al1); q15 = prelu4(q15, al1);
        unsigned short* op = y1 + ((size_t)(b*NF + f)*NT + gt0)*CH;
        STX(op, 0, x); STX(op, 1, y); STX(op, 2, z); STX(op, 3, w);
    }
}

// -------------------------------------------------------------------------
// Pass 2: conv2(16->16,k5,p2) via MFMA + PReLU -> x (n,t,16).  (R9 verbatim)
// -------------------------------------------------------------------------
__global__ __launch_bounds__(256) void conv2_kernel(
    const unsigned short* __restrict__ y1,    // (b, f, t, ch) bf16
    const float* __restrict__ w2, const float* __restrict__ b2, const float* __restrict__ a2p,
    unsigned short* __restrict__ xout)
{
    __shared__ unsigned short ylds[8*128*24];    // 48 KB: [row8][t128][ch16+pad8]
    const int b    = blockIdx.x;
    const int f0   = blockIdx.y * 4;
    const int tg   = blockIdx.z * 128;
    const int tid  = threadIdx.x;
    const int wid  = tid >> 6;
    const int lane = tid & 63;

    #pragma unroll
    for (int i = 0; i < 8; i++) {
        const int idx  = tid + i*256;        // 0..2047
        const int row  = idx >> 8;           // 0..7
        const int tt   = (idx >> 1) & 127;
        const int half = idx & 1;
        const int fr   = f0 - 2 + row;
        const int gt   = tg + tt;
        uint4 v = make_uint4(0u, 0u, 0u, 0u);
        if (fr >= 0 && fr < NF && gt < NT)
            v = *(const uint4*)(y1 + ((size_t)(b*NF + fr)*NT + gt)*CH + half*8);
        *(uint4*)&ylds[(row*128 + tt)*24 + half*8] = v;
    }
    __syncthreads();

    const int c    = lane & 15;
    const int quad = lane >> 4;
    const int f    = f0 + wid;
    if (f < NF) {
        const float al2 = a2p[0];
        short8 Bh0, Bh1, Bh2, Bl0, Bl1, Bl2;
        #define MKB2(BH, BL, Q)                                                \
            { _Pragma("unroll") for (int j = 0; j < 8; j++) {                  \
                const int ci = (quad & 1)*8 + j;                               \
                const int kk = 2*(Q) + (quad >> 1);                            \
                float w = 0.f;                                                 \
                if (kk < 5) w = w2[c*80 + ci*5 + kk];                          \
                const unsigned short hb = f2bf(w);                             \
                const float hf = bf2f((short)hb);                              \
                BH[j] = (short)hb;                                             \
                BL[j] = (short)f2bf(w - hf); } }
        MKB2(Bh0, Bl0, 0); MKB2(Bh1, Bl1, 1); MKB2(Bh2, Bl2, 2);
        #undef MKB2

        // bias per ROW: acc[r] is cout = quad*4 + r
        const f32x4 cb = {b2[quad*4 + 0], b2[quad*4 + 1],
                          b2[quad*4 + 2], b2[quad*4 + 3]};
        const int ci0 = (quad & 1)*8;
        const int r0  = wid + (quad >> 1);
        unsigned short* xo = xout + ((size_t)(b*NF + f)*NT)*CH + quad*4;

        #pragma unroll
        for (int ti = 0; ti < 8; ti++) {
            const int t = ti*16 + c;             // B col = t within the 128-slice
            const int rl2 = (r0 + 4 > 7) ? 7 : (r0 + 4);
            const short8 a0 = *(const short8*)&ylds[((r0    )*128 + t)*24 + ci0];
            const short8 a1 = *(const short8*)&ylds[((r0 + 2)*128 + t)*24 + ci0];
            const short8 a2 = *(const short8*)&ylds[((rl2   )*128 + t)*24 + ci0];
            f32x4 acc = cb;
            acc = __builtin_amdgcn_mfma_f32_16x16x32_bf16(Bl0, a0, acc, 0, 0, 0);
            acc = __builtin_amdgcn_mfma_f32_16x16x32_bf16(Bl1, a1, acc, 0, 0, 0);
            acc = __builtin_amdgcn_mfma_f32_16x16x32_bf16(Bl2, a2, acc, 0, 0, 0);
            acc = __builtin_amdgcn_mfma_f32_16x16x32_bf16(Bh0, a0, acc, 0, 0, 0);
            acc = __builtin_amdgcn_mfma_f32_16x16x32_bf16(Bh1, a1, acc, 0, 0, 0);
            acc = __builtin_amdgcn_mfma_f32_16x16x32_bf16(Bh2, a2, acc, 0, 0, 0);
            const int tt = tg + t;
            if (tt < NT) {
                float v0 = acc[0], v1 = acc[1], v2 = acc[2], v3 = acc[3];
                v0 = (v0 >= 0.f) ? v0 : al2*v0;
                v1 = (v1 >= 0.f) ? v1 : al2*v1;
                v2 = (v2 >= 0.f) ? v2 : al2*v2;
                v3 = (v3 >= 0.f) ? v3 : al2*v3;
                *(uint2*)(xo + (size_t)tt*CH) = make_uint2(pk2(v0, v1), pk2(v2, v3));
            }
        }
    }
}

// -------------------------------------------------------------------------
// GRU — R10: operand-swapped MFMA (W = srcA, data = srcB, conv2-validated
// pattern) with gate-row permutation g(4q+R) = U(q)[R],
// U = {16-23, 24-31, 0-7, 8-15}.  Each lane's GSTEP output is exactly the
// 8 h-units that lane feeds into the next step's data fragment -> the
// recurrence never leaves the lane.  h lives in 8 fp32 regs, packed with 4
// cvt_pk per step; x loads straight from global (uint4, 3-deep prefetch).
// ZERO LDS / barriers / ds ops in the loop (was ~11 ds ops + 2 barriers:
// the ~950 cyc/step of exposed LDS-turnaround latency at 0.5 waves/SIMD).
// FC uses a row-invariant W fragment -> logit in every lane, 1 masked store.
// -------------------------------------------------------------------------
__global__ __launch_bounds__(64) void gru_kernel(
    const unsigned short* __restrict__ xin,  // (NSEQ, NT, 16) bf16
    const float* __restrict__ h0,    // (NSEQ, 32)
    const float* __restrict__ w_ih,  // (96, 16)
    const float* __restrict__ w_hh,  // (96, 32)
    const float* __restrict__ b_ih, const float* __restrict__ b_hh,
    const float* __restrict__ fc_w, const float* __restrict__ fc_b,
    float* __restrict__ prob,        // (NSEQ, NT)
    float* __restrict__ hout)        // (NSEQ, 32)
{
    const int lane = threadIdx.x & 63;
    const int c    = lane & 15;
    const int quad = lane >> 4;
    const int base = blockIdx.x * 16;        // 481 blocks x 16 seq
    const float L2E = 1.4426950408889634f;

    // reader-side unit base (this lane's owned units = U(quad))
    const int ub = (quad == 0) ? 16 : (quad == 1) ? 24 : (quad == 2) ? 0 : 8;
    // builder-side unit mapping (W-frag row = c): g_A(c) = U(c>>2)[c&3]
    const int cq  = c >> 2;
    const int ubr = (cq == 0) ? 16 : (cq == 1) ? 24 : (cq == 2) ? 0 : 8;
    const int uA  = ubr + (c & 3);
    const int uB  = uA + 4;

    // ---- W fragments (srcA: row = c -> gate of unit uA/uB, k = quad*8+j) ----
    // r/z rows: w_ih k<16, w_hh k16..47; scaled L2E.
    #define BLDR(DST, CK, GROW)                                                \
        { _Pragma("unroll") for (int j = 0; j < 8; j++) {                      \
            const int k = (CK)*32 + quad*8 + j;                                \
            float wv_ = 0.f;                                                   \
            if (k < 16)      wv_ = w_ih[(GROW)*16 + k];                        \
            else if (k < 48) wv_ = w_hh[(GROW)*32 + k - 16];                   \
            DST[j] = (short)f2bf(wv_ * L2E); } }
    // xn rows (64+u): w_ih only, k<16; scaled 2*L2E.  chunk-a only.
    #define BLDX(DST, U)                                                       \
        { _Pragma("unroll") for (int j = 0; j < 8; j++) {                      \
            const int k = quad*8 + j;                                          \
            float wv_ = (k < 16) ? w_ih[(64+(U))*16 + k] : 0.f;                \
            DST[j] = (short)f2bf(wv_ * 2.f*L2E); } }
    // hn rows (64+u): w_hh, k16..47; scaled 2*L2E.
    #define BLDH(DST, CK, U)                                                   \
        { _Pragma("unroll") for (int j = 0; j < 8; j++) {                      \
            const int k = (CK)*32 + quad*8 + j;                                \
            float wv_ = (k >= 16 && k < 48) ? w_hh[(64+(U))*32 + k - 16] : 0.f;\
            DST[j] = (short)f2bf(wv_ * 2.f*L2E); } }
    // FC: row-invariant, fc_w over k16..47 (h region), unscaled.
    #define BLDF(DST, CK)                                                      \
        { _Pragma("unroll") for (int j = 0; j < 8; j++) {                      \
            const int k = (CK)*32 + quad*8 + j;                                \
            float wv_ = (k >= 16 && k < 48) ? fc_w[k - 16] : 0.f;              \
            DST[j] = (short)f2bf(wv_); } }

    short8 WRaA, WRbA, WRaB, WRbB;
    short8 WZaA, WZbA, WZaB, WZbB;
    short8 WXaA, WXaB;
    short8 WHaA, WHbA, WHaB, WHbB;
    short8 WFa, WFb;
    BLDR(WRaA, 0, uA);     BLDR(WRbA, 1, uA);
    BLDR(WRaB, 0, uB);     BLDR(WRbB, 1, uB);
    BLDR(WZaA, 0, 32+uA);  BLDR(WZbA, 1, 32+uA);
    BLDR(WZaB, 0, 32+uB);  BLDR(WZbB, 1, 32+uB);
    BLDX(WXaA, uA);        BLDX(WXaB, uB);
    BLDH(WHaA, 0, uA);     BLDH(WHbA, 1, uA);
    BLDH(WHaB, 0, uB);     BLDH(WHbB, 1, uB);
    BLDF(WFa, 0);          BLDF(WFb, 1);

    // ---- per-row biases as MFMA C (element R <-> unit ub+R / ub+4+R) ----
    const float4 biA = *(const float4*)(b_ih + ub);
    const float4 biB = *(const float4*)(b_ih + ub + 4);
    const float4 bhA = *(const float4*)(b_hh + ub);
    const float4 bhB = *(const float4*)(b_hh + ub + 4);
    const float4 ziA = *(const float4*)(b_ih + 32 + ub);
    const float4 ziB = *(const float4*)(b_ih + 36 + ub);
    const float4 zhA = *(const float4*)(b_hh + 32 + ub);
    const float4 zhB = *(const float4*)(b_hh + 36 + ub);
    const float4 niA = *(const float4*)(b_ih + 64 + ub);
    const float4 niB = *(const float4*)(b_ih + 68 + ub);
    const float4 nhA = *(const float4*)(b_hh + 64 + ub);
    const float4 nhB = *(const float4*)(b_hh + 68 + ub);
    const f32x4 cbRA = {(biA.x+bhA.x)*L2E, (biA.y+bhA.y)*L2E, (biA.z+bhA.z)*L2E, (biA.w+bhA.w)*L2E};
    const f32x4 cbRB = {(biB.x+bhB.x)*L2E, (biB.y+bhB.y)*L2E, (biB.z+bhB.z)*L2E, (biB.w+bhB.w)*L2E};
    const f32x4 cbZA = {(ziA.x+zhA.x)*L2E, (ziA.y+zhA.y)*L2E, (ziA.z+zhA.z)*L2E, (ziA.w+zhA.w)*L2E};
    const f32x4 cbZB = {(ziB.x+zhB.x)*L2E, (ziB.y+zhB.y)*L2E, (ziB.z+zhB.z)*L2E, (ziB.w+zhB.w)*L2E};
    const f32x4 cbXA = {niA.x*2.f*L2E, niA.y*2.f*L2E, niA.z*2.f*L2E, niA.w*2.f*L2E};
    const f32x4 cbXB = {niB.x*2.f*L2E, niB.y*2.f*L2E, niB.z*2.f*L2E, niB.w*2.f*L2E};
    const f32x4 cbHA = {nhA.x*2.f*L2E, nhA.y*2.f*L2E, nhA.z*2.f*L2E, nhA.w*2.f*L2E};
    const f32x4 cbHB = {nhB.x*2.f*L2E, nhB.y*2.f*L2E, nhB.z*2.f*L2E, nhB.w*2.f*L2E};
    const float fb = fc_b[0];
    const f32x4 cbF = {fb, fb, fb, fb};

    // ---- h state: 8 fp32 regs = units ub..ub+7 of seq (base+c) ----
    const float* hrow = h0 + (size_t)(base + c)*HID + ub;
    float h0_ = hrow[0], h1_ = hrow[1], h2_ = hrow[2], h3_ = hrow[3];
    float h4_ = hrow[4], h5_ = hrow[5], h6_ = hrow[6], h7_ = hrow[7];

    // ---- x pointer + 3-deep prefetch (quads 0/1 use ch 0-7 / 8-15) ----
    const unsigned short* xp = xin + ((size_t)(base + c)*NT)*CH + (quad & 1)*8;
    uint4 xcur = *(const uint4*)(xp);
    uint4 nx1  = *(const uint4*)(xp + 1*CH);
    uint4 nx2  = *(const uint4*)(xp + 2*CH);

    const short8 zero8 = {0,0,0,0,0,0,0,0};

    #define PACKH(HA)                                                          \
        { unsigned p0_, p1_, p2_, p3_;                                         \
          asm("v_cvt_pk_bf16_f32 %0, %1, %2" : "=v"(p0_) : "v"(h0_), "v"(h1_));\
          asm("v_cvt_pk_bf16_f32 %0, %1, %2" : "=v"(p1_) : "v"(h2_), "v"(h3_));\
          asm("v_cvt_pk_bf16_f32 %0, %1, %2" : "=v"(p2_) : "v"(h4_), "v"(h5_));\
          asm("v_cvt_pk_bf16_f32 %0, %1, %2" : "=v"(p3_) : "v"(h6_), "v"(h7_));\
          S8U4 hu_; hu_.u = make_uint4(p0_, p1_, p2_, p3_);                    \
          HA = hu_.s; }

    #define GS(ACR, ACZ, ACX, ACH, R, HREG)                                    \
        {                                                                      \
            const float rr = sige_(ACR[R]);                                    \
            const float zz = sige_(ACZ[R]);                                    \
            const float aa = fmaf(rr, ACH[R], ACX[R]);                         \
            const float nn = fmaf(2.f, sige_(aa), -1.f);                       \
            HREG = fmaf(zz, HREG - nn, nn);                                    \
        }

    for (int t = 0; t < NT; t++) {
        short8 ha; PACKH(ha);
        S8U4 xu; xu.u = xcur;
        const short8 a0 = (quad < 2) ? xu.s : ha;      // k0-31: x | h0-15
        const short8 a1 = (quad < 2) ? ha   : zero8;   // k32-63: h16-31 | pad

        // prefetch x(t+3)
        const int tn = (t + 3 < NT) ? t + 3 : NT - 1;
        const uint4 fx = *(const uint4*)(xp + (size_t)tn*CH);

        f32x4 aRA = __builtin_amdgcn_mfma_f32_16x16x32_bf16(WRaA, a0, cbRA, 0, 0, 0);
        f32x4 aRB = __builtin_amdgcn_mfma_f32_16x16x32_bf16(WRaB, a0, cbRB, 0, 0, 0);
        f32x4 aZA = __builtin_amdgcn_mfma_f32_16x16x32_bf16(WZaA, a0, cbZA, 0, 0, 0);
        f32x4 aZB = __builtin_amdgcn_mfma_f32_16x16x32_bf16(WZaB, a0, cbZB, 0, 0, 0);
        f32x4 aXA = __builtin_amdgcn_mfma_f32_16x16x32_bf16(WXaA, a0, cbXA, 0, 0, 0);
        f32x4 aXB = __builtin_amdgcn_mfma_f32_16x16x32_bf16(WXaB, a0, cbXB, 0, 0, 0);
        f32x4 aHA = __builtin_amdgcn_mfma_f32_16x16x32_bf16(WHaA, a0, cbHA, 0, 0, 0);
        f32x4 aHB = __builtin_amdgcn_mfma_f32_16x16x32_bf16(WHaB, a0, cbHB, 0, 0, 0);
        f32x4 aF  = __builtin_amdgcn_mfma_f32_16x16x32_bf16(WFa,  a0, cbF,  0, 0, 0);
        aRA = __builtin_amdgcn_mfma_f32_16x16x32_bf16(WRbA, a1, aRA, 0, 0, 0);
        aRB = __builtin_amdgcn_mfma_f32_16x16x32_bf16(WRbB, a1, aRB, 0, 0, 0);
        aZA = __builtin_amdgcn_mfma_f32_16x16x32_bf16(WZbA, a1, aZA, 0, 0, 0);
        aZB = __builtin_amdgcn_mfma_f32_16x16x32_bf16(WZbB, a1, aZB, 0, 0, 0);
        aHA = __builtin_amdgcn_mfma_f32_16x16x32_bf16(WHbA, a1, aHA, 0, 0, 0);
        aHB = __builtin_amdgcn_mfma_f32_16x16x32_bf16(WHbB, a1, aHB, 0, 0, 0);
        aF  = __builtin_amdgcn_mfma_f32_16x16x32_bf16(WFb,  a1, aF,  0, 0, 0);

        // prob[t-1] (aF holds the logit of h(t) in every row)
        if (t > 0 && lane < 16)
            prob[(size_t)(base + c)*NT + (t - 1)] = sig_(aF[0]);

        GS(aRA, aZA, aXA, aHA, 0, h0_);
        GS(aRA, aZA, aXA, aHA, 1, h1_);
        GS(aRA, aZA, aXA, aHA, 2, h2_);
        GS(aRA, aZA, aXA, aHA, 3, h3_);
        GS(aRB, aZB, aXB, aHB, 0, h4_);
        GS(aRB, aZB, aXB, aHB, 1, h5_);
        GS(aRB, aZB, aXB, aHB, 2, h6_);
        GS(aRB, aZB, aXB, aHB, 3, h7_);

        xcur = nx1; nx1 = nx2; nx2 = fx;
    }

    // final prob (FC on h(NT))
    {
        short8 ha; PACKH(ha);
        const short8 a0f = (quad < 2) ? zero8 : ha;
        const short8 a1f = (quad < 2) ? ha    : zero8;
        f32x4 aF = __builtin_amdgcn_mfma_f32_16x16x32_bf16(WFa, a0f, cbF, 0, 0, 0);
        aF = __builtin_amdgcn_mfma_f32_16x16x32_bf16(WFb, a1f, aF, 0, 0, 0);
        if (lane < 16)
            prob[(size_t)(base + c)*NT + (NT - 1)] = sig_(aF[0]);
    }

    // hout: each lane writes its 8 units of seq (base+c)
    float* ho = hout + (size_t)(base + c)*HID + ub;
    *(float4*)(ho)     = make_float4(h0_, h1_, h2_, h3_);
    *(float4*)(ho + 4) = make_float4(h4_, h5_, h6_, h7_);
}

// -------------------------------------------------------------------------
extern "C" void kernel_launch(void* const* d_in, const int* in_sizes, int n_in,
                              void* d_out, int out_size, void* d_ws, size_t ws_size,
                              hipStream_t stream)
{
    const float* feat = (const float*)d_in[0];
    const float* h0   = (const float*)d_in[1];
    const float* w1   = (const float*)d_in[2];
    const float* b1   = (const float*)d_in[3];
    const float* a1   = (const float*)d_in[4];
    const float* w2   = (const float*)d_in[5];
    const float* b2   = (const float*)d_in[6];
    const float* a2   = (const float*)d_in[7];
    const float* wih  = (const float*)d_in[8];
    const float* whh  = (const float*)d_in[9];
    const float* bih  = (const float*)d_in[10];
    const float* bhh  = (const float*)d_in[11];
    const float* fcw  = (const float*)d_in[12];
    const float* fcb  = (const float*)d_in[13];

    unsigned short* xbuf = (unsigned short*)d_ws;            // 123.1 MB bf16
    unsigned short* y1   = xbuf + (size_t)NSEQ*NT*CH;        // 123.1 MB bf16 (b,f,t,ch)
    float* prob = (float*)d_out;                             // (B, F, T)
    float* hout = prob + (size_t)NSEQ*NT;                    // (1, NSEQ, 32)

    dim3 c1grid(NB, 121, 2);                                 // 4 f-waves x 256 t
    conv1_kernel<<<c1grid, 256, 0, stream>>>(feat, w1, b1, a1, y1);
    dim3 c2grid(NB, 121, 4);                                 // 4 f x 128 t per block
    conv2_kernel<<<c2grid, 256, 0, stream>>>(y1, w2, b2, a2, xbuf);
    gru_kernel<<<NSEQ/16, 64, 0, stream>>>(xbuf, h0, wih, whh, bih, bhh, fcw, fcb, prob, hout);
}